// Round 1
// baseline (541.334 us; speedup 1.0000x reference)
//
#include <hip/hip_runtime.h>
#include <math.h>

#define NNODES 10000
#define NEDGES 320000
#define ETOT   (NEDGES + NNODES)
#define FINF   512
#define HD     512     // H*D
#define DHEAD  256

// ---------------- fp32 tiled GEMM: C[M,N] = A[M,K] @ B[K,N] (+bias) ----------------
__global__ __launch_bounds__(256) void gemm_tiled(const float* __restrict__ A,
    const float* __restrict__ B, const float* __restrict__ bias,
    float* __restrict__ C, int M, int N, int K)
{
    __shared__ float As[16][68];   // [k][m], row stride 272B = 17*16 (float4-aligned)
    __shared__ float Bs[16][68];   // [k][n]
    int tid = threadIdx.x;
    int tx = tid & 15, ty = tid >> 4;
    int bn = blockIdx.x * 64;
    int bm = blockIdx.y * 64;
    float acc[4][4] = {};
    for (int k0 = 0; k0 < K; k0 += 16) {
        #pragma unroll
        for (int i = 0; i < 4; ++i) {
            int lin = tid + i * 256;
            int r = lin >> 4, c = lin & 15;
            int row = bm + r;
            As[c][r] = (row < M) ? A[(size_t)row * K + k0 + c] : 0.f;
        }
        #pragma unroll
        for (int i = 0; i < 4; ++i) {
            int lin = tid + i * 256;
            int r = lin >> 6, c = lin & 63;
            Bs[r][c] = B[(size_t)(k0 + r) * N + bn + c];
        }
        __syncthreads();
        #pragma unroll
        for (int kk = 0; kk < 16; ++kk) {
            const float4 av = *reinterpret_cast<const float4*>(&As[kk][ty * 4]);
            const float4 bv = *reinterpret_cast<const float4*>(&Bs[kk][tx * 4]);
            float a[4] = {av.x, av.y, av.z, av.w};
            float b[4] = {bv.x, bv.y, bv.z, bv.w};
            #pragma unroll
            for (int i = 0; i < 4; ++i)
                #pragma unroll
                for (int j = 0; j < 4; ++j)
                    acc[i][j] = fmaf(a[i], b[j], acc[i][j]);
        }
        __syncthreads();
    }
    #pragma unroll
    for (int i = 0; i < 4; ++i) {
        int row = bm + ty * 4 + i;
        if (row >= M) continue;
        #pragma unroll
        for (int j = 0; j < 4; ++j) {
            int col = bn + tx * 4 + j;
            float v = acc[i][j];
            if (bias) v += bias[col];
            C[(size_t)row * N + col] = v;
        }
    }
}

// ---------------- attention coefficients a_src/a_dst [N,2] ----------------
__global__ __launch_bounds__(64) void attn_coef(const float* __restrict__ h,
    const float* __restrict__ att_s, const float* __restrict__ att_d,
    float* __restrict__ a_src, float* __restrict__ a_dst)
{
    int n = blockIdx.x, lane = threadIdx.x;
    const float* hr = h + (size_t)n * HD;
    float s0 = 0, s1 = 0, d0 = 0, d1 = 0;
    for (int j = lane; j < DHEAD; j += 64) {
        float v0 = hr[j], v1 = hr[DHEAD + j];
        s0 = fmaf(v0, att_s[j], s0);
        s1 = fmaf(v1, att_s[DHEAD + j], s1);
        d0 = fmaf(v0, att_d[j], d0);
        d1 = fmaf(v1, att_d[DHEAD + j], d1);
    }
    #pragma unroll
    for (int off = 32; off > 0; off >>= 1) {
        s0 += __shfl_down(s0, off);
        s1 += __shfl_down(s1, off);
        d0 += __shfl_down(d0, off);
        d1 += __shfl_down(d1, off);
    }
    if (lane == 0) {
        a_src[2 * n] = s0; a_src[2 * n + 1] = s1;
        a_dst[2 * n] = d0; a_dst[2 * n + 1] = d1;
    }
}

// ---------------- degree histogram over dst (incl. self-loops) ----------------
__global__ __launch_bounds__(256) void hist_kernel(const int* __restrict__ ei, int* __restrict__ deg)
{
    int e = blockIdx.x * 256 + threadIdx.x;
    if (e >= ETOT) return;
    int d = (e < NEDGES) ? ei[NEDGES + e] : (e - NEDGES);
    atomicAdd(&deg[d], 1);
}

// ---------------- single-block exclusive scan of deg -> row_start ----------------
__global__ __launch_bounds__(256) void scan_kernel(const int* __restrict__ deg, int* __restrict__ rowst)
{
    __shared__ int part[256];
    int t = threadIdx.x;
    const int chunk = (NNODES + 255) / 256;   // 40
    int base = t * chunk;
    int s = 0;
    for (int i = 0; i < chunk; ++i) {
        int n = base + i;
        if (n < NNODES) s += deg[n];
    }
    part[t] = s;
    __syncthreads();
    for (int off = 1; off < 256; off <<= 1) {
        int v = 0;
        if (t >= off) v = part[t - off];
        __syncthreads();
        if (t >= off) part[t] += v;
        __syncthreads();
    }
    int run = (t == 0) ? 0 : part[t - 1];
    for (int i = 0; i < chunk; ++i) {
        int n = base + i;
        if (n < NNODES) { rowst[n] = run; run += deg[n]; }
    }
}

// ---------------- scatter edges into CSR slots; precompute p = exp(lrelu(e)) ----------------
__global__ __launch_bounds__(256) void scatter_kernel(const int* __restrict__ ei,
    const float* __restrict__ a_src, const float* __restrict__ a_dst,
    const int* __restrict__ rowst, int* __restrict__ cnt,
    int* __restrict__ esrc, float* __restrict__ p0, float* __restrict__ p1)
{
    int e = blockIdx.x * 256 + threadIdx.x;
    if (e >= ETOT) return;
    int s, d;
    if (e < NEDGES) { s = ei[e]; d = ei[NEDGES + e]; } else { s = d = e - NEDGES; }
    int pos = rowst[d] + atomicAdd(&cnt[d], 1);
    esrc[pos] = s;
    float e0 = a_src[2 * s] + a_dst[2 * d];
    e0 = (e0 > 0.f) ? e0 : 0.2f * e0;
    float e1 = a_src[2 * s + 1] + a_dst[2 * d + 1];
    e1 = (e1 > 0.f) ? e1 : 0.2f * e1;
    p0[pos] = expf(e0);
    p1[pos] = expf(e1);
}

// ---------------- per-node aggregation: y = lrelu( (Σ p·h[src])/Σp + b_conv ) ----------------
__global__ __launch_bounds__(256) void aggregate_kernel(const float* __restrict__ h,
    const int* __restrict__ rowst, const int* __restrict__ deg, const int* __restrict__ esrc,
    const float* __restrict__ p0, const float* __restrict__ p1,
    const float* __restrict__ b_conv, float* __restrict__ y)
{
    int n = blockIdx.x, t = threadIdx.x;
    int s = rowst[n], len = deg[n];
    float acc0 = 0, acc1 = 0, den0 = 0, den1 = 0;
    for (int k = 0; k < len; ++k) {
        int src = esrc[s + k];
        float q0 = p0[s + k], q1 = p1[s + k];
        const float* hr = h + (size_t)src * HD;
        acc0 = fmaf(q0, hr[t], acc0);
        acc1 = fmaf(q1, hr[DHEAD + t], acc1);
        den0 += q0; den1 += q1;
    }
    float o0 = acc0 / den0 + b_conv[t];
    float o1 = acc1 / den1 + b_conv[DHEAD + t];
    y[(size_t)n * HD + t]         = (o0 > 0.f) ? o0 : 0.01f * o0;
    y[(size_t)n * HD + DHEAD + t] = (o1 > 0.f) ? o1 : 0.01f * o1;
}

// ---------------- column sums + sum of squares (for BN batch stats) ----------------
__global__ __launch_bounds__(256) void colstats(const float* __restrict__ z, float* __restrict__ sums, int C)
{
    int t = threadIdx.x;
    int c = t & (C - 1);
    int rl = t / C;
    int rpi = 256 / C;
    float s = 0, s2 = 0;
    for (int r = blockIdx.x * rpi + rl; r < NNODES; r += gridDim.x * rpi) {
        float v = z[(size_t)r * C + c];
        s += v;
        s2 = fmaf(v, v, s2);
    }
    __shared__ float sh[256], sh2[256];
    sh[t] = s; sh2[t] = s2;
    __syncthreads();
    for (int off = 128; off >= C; off >>= 1) {
        if (t < off) { sh[t] += sh[t + off]; sh2[t] += sh2[t + off]; }
        __syncthreads();
    }
    if (t < C) {
        atomicAdd(&sums[c], sh[t]);
        atomicAdd(&sums[C + c], sh2[t]);
    }
}

// ---------------- apply BN (batch stats, biased var) + leaky relu 0.01, in place ----------------
__global__ __launch_bounds__(256) void bn_lrelu(float* __restrict__ z, const float* __restrict__ sums,
    const float* __restrict__ g, const float* __restrict__ beta, int C)
{
    int idx = blockIdx.x * 256 + threadIdx.x;
    if (idx >= NNODES * C) return;
    int c = idx & (C - 1);
    float m = sums[c] * (1.f / NNODES);
    float v = sums[C + c] * (1.f / NNODES) - m * m;
    float r = rsqrtf(v + 1e-5f);
    float xv = z[idx];
    xv = g[c] * (xv - m) * r + beta[c];
    z[idx] = (xv > 0.f) ? xv : 0.01f * xv;
}

// ---------------- final dense 64 -> 3 ----------------
__global__ __launch_bounds__(256) void dense3_kernel(const float* __restrict__ z2,
    const float* __restrict__ w3, const float* __restrict__ b3, float* __restrict__ y3)
{
    int n = blockIdx.x * 256 + threadIdx.x;
    if (n >= NNODES) return;
    float o0 = b3[0], o1 = b3[1], o2 = b3[2];
    const float* zr = z2 + (size_t)n * 64;
    #pragma unroll
    for (int j = 0; j < 64; ++j) {
        float v = zr[j];
        o0 = fmaf(v, w3[3 * j],     o0);
        o1 = fmaf(v, w3[3 * j + 1], o1);
        o2 = fmaf(v, w3[3 * j + 2], o2);
    }
    y3[3 * n] = o0; y3[3 * n + 1] = o1; y3[3 * n + 2] = o2;
}

// ---------------- pairwise euclidean distances [N,N] ----------------
__global__ __launch_bounds__(256) void dist_kernel(const float* __restrict__ y3, float* __restrict__ out)
{
    int j = blockIdx.x * 256 + threadIdx.x;
    int i0 = blockIdx.y * 64;
    bool jv = (j < NNODES);
    float xj = 0, yj = 0, zj = 0;
    if (jv) { xj = y3[3 * j]; yj = y3[3 * j + 1]; zj = y3[3 * j + 2]; }
    int iend = (i0 + 64 < NNODES) ? (i0 + 64) : NNODES;
    for (int i = i0; i < iend; ++i) {
        float xi = y3[3 * i], yi = y3[3 * i + 1], zi = y3[3 * i + 2];
        if (jv) {
            float dx = xi - xj, dy = yi - yj, dz = zi - zj;
            float d2 = fmaf(dx, dx, fmaf(dy, dy, dz * dz));
            out[(size_t)i * NNODES + j] = (d2 > 1e-12f) ? sqrtf(d2) : 0.f;
        }
    }
}

extern "C" void kernel_launch(void* const* d_in, const int* in_sizes, int n_in,
                              void* d_out, int out_size, void* d_ws, size_t ws_size,
                              hipStream_t stream)
{
    (void)in_sizes; (void)n_in; (void)out_size; (void)ws_size;
    const float* x      = (const float*)d_in[0];
    const int*   ei     = (const int*)  d_in[1];
    const float* w_conv = (const float*)d_in[2];
    const float* att_s  = (const float*)d_in[3];
    const float* att_d  = (const float*)d_in[4];
    const float* b_conv = (const float*)d_in[5];
    const float* w_a  = (const float*)d_in[6];
    const float* b_a  = (const float*)d_in[7];
    const float* g_a  = (const float*)d_in[8];
    const float* be_a = (const float*)d_in[9];
    const float* w_1  = (const float*)d_in[10];
    const float* b_1  = (const float*)d_in[11];
    const float* g_1  = (const float*)d_in[12];
    const float* be_1 = (const float*)d_in[13];
    const float* w_2  = (const float*)d_in[14];
    const float* b_2  = (const float*)d_in[15];
    const float* g_2  = (const float*)d_in[16];
    const float* be_2 = (const float*)d_in[17];
    const float* w_3  = (const float*)d_in[18];
    const float* b_3  = (const float*)d_in[19];

    char* ws = (char*)d_ws;
    size_t off = 0;
    auto take = [&](size_t bytes) {
        char* p = ws + off;
        off = (off + bytes + 255) & ~(size_t)255;
        return p;
    };
    float* h    = (float*)take((size_t)NNODES * HD * 4);       // 20.48 MB (reused below)
    float* y    = (float*)take((size_t)NNODES * HD * 4);       // 20.48 MB
    float* z_a  = (float*)take((size_t)NNODES * 256 * 4);      // 10.24 MB
    float* a_src= (float*)take((size_t)NNODES * 2 * 4);
    float* a_dst= (float*)take((size_t)NNODES * 2 * 4);
    int*   rowst= (int*)  take((size_t)NNODES * 4);
    int*   esrc = (int*)  take((size_t)ETOT * 4);
    float* p0   = (float*)take((size_t)ETOT * 4);
    float* p1   = (float*)take((size_t)ETOT * 4);
    char*  zblk = take(40000 + 40000 + 2048 + 1024 + 512);     // zeroed block
    int*   deg  = (int*)(zblk);
    int*   cnt  = (int*)(zblk + 40000);
    float* stA  = (float*)(zblk + 80000);                      // 2*256 floats
    float* st1  = (float*)(zblk + 82048);                      // 2*128 floats
    float* st2  = (float*)(zblk + 83072);                      // 2*64 floats
    // h region is dead after aggregate_kernel; reuse it for later layers:
    float* z_1 = h;                                            // [N,128]
    float* z_2 = h + (size_t)NNODES * 128;                     // [N,64]
    float* y3  = h + (size_t)NNODES * 192;                     // [N,3]

    hipMemsetAsync(zblk, 0, 40000 + 40000 + 2048 + 1024 + 512, stream);

    dim3 b256(256), b64(64);
    // h = x @ w_conv
    gemm_tiled<<<dim3(HD / 64, (NNODES + 63) / 64), b256, 0, stream>>>(x, w_conv, nullptr, h, NNODES, HD, FINF);
    attn_coef<<<dim3(NNODES), b64, 0, stream>>>(h, att_s, att_d, a_src, a_dst);
    hist_kernel<<<dim3((ETOT + 255) / 256), b256, 0, stream>>>(ei, deg);
    scan_kernel<<<dim3(1), b256, 0, stream>>>(deg, rowst);
    scatter_kernel<<<dim3((ETOT + 255) / 256), b256, 0, stream>>>(ei, a_src, a_dst, rowst, cnt, esrc, p0, p1);
    aggregate_kernel<<<dim3(NNODES), b256, 0, stream>>>(h, rowst, deg, esrc, p0, p1, b_conv, y);
    // densea 512->256 + BN + lrelu
    gemm_tiled<<<dim3(256 / 64, (NNODES + 63) / 64), b256, 0, stream>>>(y, w_a, b_a, z_a, NNODES, 256, 512);
    colstats<<<dim3(80), b256, 0, stream>>>(z_a, stA, 256);
    bn_lrelu<<<dim3((NNODES * 256 + 255) / 256), b256, 0, stream>>>(z_a, stA, g_a, be_a, 256);
    // dense1 256->128 + BN + lrelu
    gemm_tiled<<<dim3(128 / 64, (NNODES + 63) / 64), b256, 0, stream>>>(z_a, w_1, b_1, z_1, NNODES, 128, 256);
    colstats<<<dim3(80), b256, 0, stream>>>(z_1, st1, 128);
    bn_lrelu<<<dim3((NNODES * 128 + 255) / 256), b256, 0, stream>>>(z_1, st1, g_1, be_1, 128);
    // dense2 128->64 + BN + lrelu
    gemm_tiled<<<dim3(64 / 64, (NNODES + 63) / 64), b256, 0, stream>>>(z_1, w_2, b_2, z_2, NNODES, 64, 128);
    colstats<<<dim3(80), b256, 0, stream>>>(z_2, st2, 64);
    bn_lrelu<<<dim3((NNODES * 64 + 255) / 256), b256, 0, stream>>>(z_2, st2, g_2, be_2, 64);
    // dense3 64->3
    dense3_kernel<<<dim3((NNODES + 255) / 256), b256, 0, stream>>>(z_2, w_3, b_3, y3);
    // pairwise distances
    dist_kernel<<<dim3((NNODES + 255) / 256, (NNODES + 63) / 64), b256, 0, stream>>>(y3, (float*)d_out);
}

// Round 2
// 438.695 us; speedup vs baseline: 1.2340x; 1.2340x over previous
//
#include <hip/hip_runtime.h>
#include <math.h>

#define NNODES 10000
#define NEDGES 320000
#define ETOT   (NEDGES + NNODES)
#define FINF   512
#define HD     512     // H*D
#define DHEAD  256

typedef __attribute__((ext_vector_type(8))) short bf16x8;
typedef __attribute__((ext_vector_type(4))) float f32x4;

__device__ __forceinline__ ushort f2bf(float f) {
    unsigned u = __builtin_bit_cast(unsigned, f);
    unsigned r = (u + 0x7FFFu + ((u >> 16) & 1u)) >> 16;
    return (ushort)r;
}
__device__ __forceinline__ float bf2f(ushort h) {
    unsigned u = ((unsigned)h) << 16;
    return __builtin_bit_cast(float, u);
}

// ---------------- fp32 -> bf16 hi/lo split (vectorized) ----------------
__global__ __launch_bounds__(256) void split_kernel(const float* __restrict__ x,
    ushort* __restrict__ hi, ushort* __restrict__ lo, int n4)
{
    int i = blockIdx.x * 256 + threadIdx.x;
    if (i >= n4) return;
    float4 v = ((const float4*)x)[i];
    ushort4 h, l;
    h.x = f2bf(v.x); l.x = f2bf(v.x - bf2f(h.x));
    h.y = f2bf(v.y); l.y = f2bf(v.y - bf2f(h.y));
    h.z = f2bf(v.z); l.z = f2bf(v.z - bf2f(h.z));
    h.w = f2bf(v.w); l.w = f2bf(v.w - bf2f(h.w));
    ((ushort4*)hi)[i] = h;
    ((ushort4*)lo)[i] = l;
}

// ---------------- weight transpose + hi/lo split: w[K][N] -> t[N][K] ----------------
__global__ __launch_bounds__(256) void wsplit_kernel(const float* __restrict__ w,
    ushort* __restrict__ th, ushort* __restrict__ tl, int K, int N)
{
    int idx = blockIdx.x * 256 + threadIdx.x;
    if (idx >= K * N) return;
    int n = idx / K, k = idx - n * K;
    float v = w[(size_t)k * N + n];
    ushort h = f2bf(v);
    th[idx] = h;
    tl[idx] = f2bf(v - bf2f(h));
}

// ---------------- bf16-MFMA GEMM with hi/lo split: C[M,N] = A[M,K] @ Bt[N,K]^T (+bias) ----------------
// A given as Ah/Al [M][K] bf16, B as Bh/Bl [N][K] bf16 (pre-transposed).
__global__ __launch_bounds__(256) void gemm_mfma(
    const ushort* __restrict__ Ah, const ushort* __restrict__ Al,
    const ushort* __restrict__ Bh, const ushort* __restrict__ Bl,
    const float* __restrict__ bias, float* __restrict__ C,
    int M, int N, int K)
{
    __shared__ ushort sA[2][4][64][8];   // [hi/lo][kblk][row][8k]
    __shared__ ushort sB[2][4][64][8];
    int tid = threadIdx.x;
    int lane = tid & 63, wave = tid >> 6;
    int wr = wave >> 1, wc = wave & 1;     // wave sub-tile (32x32)
    int bm = blockIdx.y * 64, bn = blockIdx.x * 64;
    int srow = tid >> 2;                   // staging: 0..63
    int skb  = tid & 3;                    // staging k-block 0..3
    int arow = bm + srow;
    const size_t aoff = (size_t)arow * K + skb * 8;
    const size_t boff = (size_t)(bn + srow) * K + skb * 8;

    f32x4 acc[2][2];
    #pragma unroll
    for (int i = 0; i < 2; ++i)
        #pragma unroll
        for (int j = 0; j < 2; ++j)
            acc[i][j] = (f32x4){0.f, 0.f, 0.f, 0.f};

    int kb = lane >> 4, mrow = lane & 15;

    for (int k0 = 0; k0 < K; k0 += 32) {
        int4 va_h = {0, 0, 0, 0}, va_l = {0, 0, 0, 0};
        if (arow < M) {
            va_h = *(const int4*)(Ah + aoff + k0);
            va_l = *(const int4*)(Al + aoff + k0);
        }
        int4 vb_h = *(const int4*)(Bh + boff + k0);
        int4 vb_l = *(const int4*)(Bl + boff + k0);
        __syncthreads();   // previous iteration's frag reads done
        *(int4*)&sA[0][skb][srow][0] = va_h;
        *(int4*)&sA[1][skb][srow][0] = va_l;
        *(int4*)&sB[0][skb][srow][0] = vb_h;
        *(int4*)&sB[1][skb][srow][0] = vb_l;
        __syncthreads();

        bf16x8 fah[2], fal[2], fbh[2], fbl[2];
        #pragma unroll
        for (int fi = 0; fi < 2; ++fi) {
            int r = wr * 32 + fi * 16 + mrow;
            fah[fi] = *(const bf16x8*)&sA[0][kb][r][0];
            fal[fi] = *(const bf16x8*)&sA[1][kb][r][0];
        }
        #pragma unroll
        for (int fj = 0; fj < 2; ++fj) {
            int r = wc * 32 + fj * 16 + mrow;
            fbh[fj] = *(const bf16x8*)&sB[0][kb][r][0];
            fbl[fj] = *(const bf16x8*)&sB[1][kb][r][0];
        }
        #pragma unroll
        for (int fi = 0; fi < 2; ++fi)
            #pragma unroll
            for (int fj = 0; fj < 2; ++fj) {
                acc[fi][fj] = __builtin_amdgcn_mfma_f32_16x16x32_bf16(fah[fi], fbh[fj], acc[fi][fj], 0, 0, 0);
                acc[fi][fj] = __builtin_amdgcn_mfma_f32_16x16x32_bf16(fah[fi], fbl[fj], acc[fi][fj], 0, 0, 0);
                acc[fi][fj] = __builtin_amdgcn_mfma_f32_16x16x32_bf16(fal[fi], fbh[fj], acc[fi][fj], 0, 0, 0);
            }
    }

    // epilogue: D row=(lane>>4)*4+reg (A side), col=lane&15 (B side)
    #pragma unroll
    for (int fi = 0; fi < 2; ++fi) {
        int crow0 = bm + wr * 32 + fi * 16 + (lane >> 4) * 4;
        #pragma unroll
        for (int fj = 0; fj < 2; ++fj) {
            int ccol = bn + wc * 32 + fj * 16 + (lane & 15);
            float bv = bias ? bias[ccol] : 0.f;
            #pragma unroll
            for (int r = 0; r < 4; ++r) {
                int row = crow0 + r;
                if (row < M) C[(size_t)row * N + ccol] = acc[fi][fj][r] + bv;
            }
        }
    }
}

// ---------------- attention coefficients a_src/a_dst [N,2] ----------------
__global__ __launch_bounds__(64) void attn_coef(const float* __restrict__ h,
    const float* __restrict__ att_s, const float* __restrict__ att_d,
    float* __restrict__ a_src, float* __restrict__ a_dst)
{
    int n = blockIdx.x, lane = threadIdx.x;
    const float* hr = h + (size_t)n * HD;
    float s0 = 0, s1 = 0, d0 = 0, d1 = 0;
    for (int j = lane; j < DHEAD; j += 64) {
        float v0 = hr[j], v1 = hr[DHEAD + j];
        s0 = fmaf(v0, att_s[j], s0);
        s1 = fmaf(v1, att_s[DHEAD + j], s1);
        d0 = fmaf(v0, att_d[j], d0);
        d1 = fmaf(v1, att_d[DHEAD + j], d1);
    }
    #pragma unroll
    for (int off = 32; off > 0; off >>= 1) {
        s0 += __shfl_down(s0, off);
        s1 += __shfl_down(s1, off);
        d0 += __shfl_down(d0, off);
        d1 += __shfl_down(d1, off);
    }
    if (lane == 0) {
        a_src[2 * n] = s0; a_src[2 * n + 1] = s1;
        a_dst[2 * n] = d0; a_dst[2 * n + 1] = d1;
    }
}

// ---------------- degree histogram over dst (incl. self-loops) ----------------
__global__ __launch_bounds__(256) void hist_kernel(const int* __restrict__ ei, int* __restrict__ deg)
{
    int e = blockIdx.x * 256 + threadIdx.x;
    if (e >= ETOT) return;
    int d = (e < NEDGES) ? ei[NEDGES + e] : (e - NEDGES);
    atomicAdd(&deg[d], 1);
}

// ---------------- single-block exclusive scan of deg -> row_start ----------------
__global__ __launch_bounds__(256) void scan_kernel(const int* __restrict__ deg, int* __restrict__ rowst)
{
    __shared__ int part[256];
    int t = threadIdx.x;
    const int chunk = (NNODES + 255) / 256;   // 40
    int base = t * chunk;
    int s = 0;
    for (int i = 0; i < chunk; ++i) {
        int n = base + i;
        if (n < NNODES) s += deg[n];
    }
    part[t] = s;
    __syncthreads();
    for (int off = 1; off < 256; off <<= 1) {
        int v = 0;
        if (t >= off) v = part[t - off];
        __syncthreads();
        if (t >= off) part[t] += v;
        __syncthreads();
    }
    int run = (t == 0) ? 0 : part[t - 1];
    for (int i = 0; i < chunk; ++i) {
        int n = base + i;
        if (n < NNODES) { rowst[n] = run; run += deg[n]; }
    }
}

// ---------------- scatter edges into CSR slots; precompute p = exp(lrelu(e)) ----------------
__global__ __launch_bounds__(256) void scatter_kernel(const int* __restrict__ ei,
    const float* __restrict__ a_src, const float* __restrict__ a_dst,
    const int* __restrict__ rowst, int* __restrict__ cnt,
    int* __restrict__ esrc, float* __restrict__ p0, float* __restrict__ p1)
{
    int e = blockIdx.x * 256 + threadIdx.x;
    if (e >= ETOT) return;
    int s, d;
    if (e < NEDGES) { s = ei[e]; d = ei[NEDGES + e]; } else { s = d = e - NEDGES; }
    int pos = rowst[d] + atomicAdd(&cnt[d], 1);
    esrc[pos] = s;
    float e0 = a_src[2 * s] + a_dst[2 * d];
    e0 = (e0 > 0.f) ? e0 : 0.2f * e0;
    float e1 = a_src[2 * s + 1] + a_dst[2 * d + 1];
    e1 = (e1 > 0.f) ? e1 : 0.2f * e1;
    p0[pos] = expf(e0);
    p1[pos] = expf(e1);
}

// ---------------- per-node aggregation: y = lrelu( (Σ p·h[src])/Σp + b_conv ) ----------------
__global__ __launch_bounds__(256) void aggregate_kernel(const float* __restrict__ h,
    const int* __restrict__ rowst, const int* __restrict__ deg, const int* __restrict__ esrc,
    const float* __restrict__ p0, const float* __restrict__ p1,
    const float* __restrict__ b_conv, float* __restrict__ y)
{
    int n = blockIdx.x, t = threadIdx.x;
    int s = rowst[n], len = deg[n];
    float acc0 = 0, acc1 = 0, den0 = 0, den1 = 0;
    for (int k = 0; k < len; ++k) {
        int src = esrc[s + k];
        float q0 = p0[s + k], q1 = p1[s + k];
        const float* hr = h + (size_t)src * HD;
        acc0 = fmaf(q0, hr[t], acc0);
        acc1 = fmaf(q1, hr[DHEAD + t], acc1);
        den0 += q0; den1 += q1;
    }
    float o0 = acc0 / den0 + b_conv[t];
    float o1 = acc1 / den1 + b_conv[DHEAD + t];
    y[(size_t)n * HD + t]         = (o0 > 0.f) ? o0 : 0.01f * o0;
    y[(size_t)n * HD + DHEAD + t] = (o1 > 0.f) ? o1 : 0.01f * o1;
}

// ---------------- column sums + sum of squares (for BN batch stats) ----------------
__global__ __launch_bounds__(256) void colstats(const float* __restrict__ z, float* __restrict__ sums, int C)
{
    int t = threadIdx.x;
    int c = t & (C - 1);
    int rl = t / C;
    int rpi = 256 / C;
    float s = 0, s2 = 0;
    for (int r = blockIdx.x * rpi + rl; r < NNODES; r += gridDim.x * rpi) {
        float v = z[(size_t)r * C + c];
        s += v;
        s2 = fmaf(v, v, s2);
    }
    __shared__ float sh[256], sh2[256];
    sh[t] = s; sh2[t] = s2;
    __syncthreads();
    for (int off = 128; off >= C; off >>= 1) {
        if (t < off) { sh[t] += sh[t + off]; sh2[t] += sh2[t + off]; }
        __syncthreads();
    }
    if (t < C) {
        atomicAdd(&sums[c], sh[t]);
        atomicAdd(&sums[C + c], sh2[t]);
    }
}

// ---------------- apply BN (batch stats, biased var) + leaky relu 0.01, in place ----------------
__global__ __launch_bounds__(256) void bn_lrelu(float* __restrict__ z, const float* __restrict__ sums,
    const float* __restrict__ g, const float* __restrict__ beta, int C)
{
    int idx = blockIdx.x * 256 + threadIdx.x;
    if (idx >= NNODES * C) return;
    int c = idx & (C - 1);
    float m = sums[c] * (1.f / NNODES);
    float v = sums[C + c] * (1.f / NNODES) - m * m;
    float r = rsqrtf(v + 1e-5f);
    float xv = z[idx];
    xv = g[c] * (xv - m) * r + beta[c];
    z[idx] = (xv > 0.f) ? xv : 0.01f * xv;
}

// ---------------- final dense 64 -> 3 ----------------
__global__ __launch_bounds__(256) void dense3_kernel(const float* __restrict__ z2,
    const float* __restrict__ w3, const float* __restrict__ b3, float* __restrict__ y3)
{
    int n = blockIdx.x * 256 + threadIdx.x;
    if (n >= NNODES) return;
    float o0 = b3[0], o1 = b3[1], o2 = b3[2];
    const float* zr = z2 + (size_t)n * 64;
    #pragma unroll
    for (int j = 0; j < 64; ++j) {
        float v = zr[j];
        o0 = fmaf(v, w3[3 * j],     o0);
        o1 = fmaf(v, w3[3 * j + 1], o1);
        o2 = fmaf(v, w3[3 * j + 2], o2);
    }
    y3[3 * n] = o0; y3[3 * n + 1] = o1; y3[3 * n + 2] = o2;
}

// ---------------- pairwise euclidean distances [N,N] ----------------
__global__ __launch_bounds__(256) void dist_kernel(const float* __restrict__ y3, float* __restrict__ out)
{
    int j = blockIdx.x * 256 + threadIdx.x;
    int i0 = blockIdx.y * 64;
    bool jv = (j < NNODES);
    float xj = 0, yj = 0, zj = 0;
    if (jv) { xj = y3[3 * j]; yj = y3[3 * j + 1]; zj = y3[3 * j + 2]; }
    int iend = (i0 + 64 < NNODES) ? (i0 + 64) : NNODES;
    for (int i = i0; i < iend; ++i) {
        float xi = y3[3 * i], yi = y3[3 * i + 1], zi = y3[3 * i + 2];
        if (jv) {
            float dx = xi - xj, dy = yi - yj, dz = zi - zj;
            float d2 = fmaf(dx, dx, fmaf(dy, dy, dz * dz));
            out[(size_t)i * NNODES + j] = (d2 > 1e-12f) ? sqrtf(d2) : 0.f;
        }
    }
}

extern "C" void kernel_launch(void* const* d_in, const int* in_sizes, int n_in,
                              void* d_out, int out_size, void* d_ws, size_t ws_size,
                              hipStream_t stream)
{
    (void)in_sizes; (void)n_in; (void)out_size; (void)ws_size;
    const float* x      = (const float*)d_in[0];
    const int*   ei     = (const int*)  d_in[1];
    const float* w_conv = (const float*)d_in[2];
    const float* att_s  = (const float*)d_in[3];
    const float* att_d  = (const float*)d_in[4];
    const float* b_conv = (const float*)d_in[5];
    const float* w_a  = (const float*)d_in[6];
    const float* b_a  = (const float*)d_in[7];
    const float* g_a  = (const float*)d_in[8];
    const float* be_a = (const float*)d_in[9];
    const float* w_1  = (const float*)d_in[10];
    const float* b_1  = (const float*)d_in[11];
    const float* g_1  = (const float*)d_in[12];
    const float* be_1 = (const float*)d_in[13];
    const float* w_2  = (const float*)d_in[14];
    const float* b_2  = (const float*)d_in[15];
    const float* g_2  = (const float*)d_in[16];
    const float* be_2 = (const float*)d_in[17];
    const float* w_3  = (const float*)d_in[18];
    const float* b_3  = (const float*)d_in[19];

    char* ws = (char*)d_ws;
    size_t off = 0;
    auto take = [&](size_t bytes) {
        char* p = ws + off;
        off = (off + bytes + 255) & ~(size_t)255;
        return p;
    };
    float* h    = (float*)take((size_t)NNODES * HD * 4);
    float* y    = (float*)take((size_t)NNODES * HD * 4);
    float* z_a  = (float*)take((size_t)NNODES * 256 * 4);
    float* z_1  = (float*)take((size_t)NNODES * 128 * 4);
    float* z_2  = (float*)take((size_t)NNODES * 64 * 4);
    float* y3   = (float*)take((size_t)NNODES * 3 * 4);
    ushort* xh  = (ushort*)take((size_t)NNODES * FINF * 2);
    ushort* xl  = (ushort*)take((size_t)NNODES * FINF * 2);
    ushort* yh  = (ushort*)take((size_t)NNODES * HD * 2);
    ushort* yl  = (ushort*)take((size_t)NNODES * HD * 2);
    ushort* zah = (ushort*)take((size_t)NNODES * 256 * 2);
    ushort* zal = (ushort*)take((size_t)NNODES * 256 * 2);
    ushort* z1h = (ushort*)take((size_t)NNODES * 128 * 2);
    ushort* z1l = (ushort*)take((size_t)NNODES * 128 * 2);
    ushort* wch = (ushort*)take((size_t)512 * 512 * 2);
    ushort* wcl = (ushort*)take((size_t)512 * 512 * 2);
    ushort* wah = (ushort*)take((size_t)256 * 512 * 2);
    ushort* wal = (ushort*)take((size_t)256 * 512 * 2);
    ushort* w1h = (ushort*)take((size_t)128 * 256 * 2);
    ushort* w1l = (ushort*)take((size_t)128 * 256 * 2);
    ushort* w2h = (ushort*)take((size_t)64 * 128 * 2);
    ushort* w2l = (ushort*)take((size_t)64 * 128 * 2);
    float* a_src= (float*)take((size_t)NNODES * 2 * 4);
    float* a_dst= (float*)take((size_t)NNODES * 2 * 4);
    int*   rowst= (int*)  take((size_t)NNODES * 4);
    int*   esrc = (int*)  take((size_t)ETOT * 4);
    float* p0   = (float*)take((size_t)ETOT * 4);
    float* p1   = (float*)take((size_t)ETOT * 4);
    char*  zblk = take(40000 + 40000 + 2048 + 1024 + 512);
    int*   deg  = (int*)(zblk);
    int*   cnt  = (int*)(zblk + 40000);
    float* stA  = (float*)(zblk + 80000);
    float* st1  = (float*)(zblk + 82048);
    float* st2  = (float*)(zblk + 83072);

    hipMemsetAsync(zblk, 0, 40000 + 40000 + 2048 + 1024 + 512, stream);

    dim3 b256(256), b64(64);
    const int MT = (NNODES + 63) / 64;   // 157 M-tiles

    // prep: split x, transpose+split all weights
    split_kernel<<<dim3((NNODES * FINF / 4 + 255) / 256), b256, 0, stream>>>(x, xh, xl, NNODES * FINF / 4);
    wsplit_kernel<<<dim3((512 * 512 + 255) / 256), b256, 0, stream>>>(w_conv, wch, wcl, 512, 512);
    wsplit_kernel<<<dim3((512 * 256 + 255) / 256), b256, 0, stream>>>(w_a, wah, wal, 512, 256);
    wsplit_kernel<<<dim3((256 * 128 + 255) / 256), b256, 0, stream>>>(w_1, w1h, w1l, 256, 128);
    wsplit_kernel<<<dim3((128 * 64 + 255) / 256), b256, 0, stream>>>(w_2, w2h, w2l, 128, 64);

    // h = x @ w_conv  (MFMA)
    gemm_mfma<<<dim3(HD / 64, MT), b256, 0, stream>>>(xh, xl, wch, wcl, nullptr, h, NNODES, HD, FINF);

    attn_coef<<<dim3(NNODES), b64, 0, stream>>>(h, att_s, att_d, a_src, a_dst);
    hist_kernel<<<dim3((ETOT + 255) / 256), b256, 0, stream>>>(ei, deg);
    scan_kernel<<<dim3(1), b256, 0, stream>>>(deg, rowst);
    scatter_kernel<<<dim3((ETOT + 255) / 256), b256, 0, stream>>>(ei, a_src, a_dst, rowst, cnt, esrc, p0, p1);
    aggregate_kernel<<<dim3(NNODES), b256, 0, stream>>>(h, rowst, deg, esrc, p0, p1, b_conv, y);

    // densea 512->256 + BN + lrelu
    split_kernel<<<dim3((NNODES * HD / 4 + 255) / 256), b256, 0, stream>>>(y, yh, yl, NNODES * HD / 4);
    gemm_mfma<<<dim3(256 / 64, MT), b256, 0, stream>>>(yh, yl, wah, wal, b_a, z_a, NNODES, 256, 512);
    colstats<<<dim3(80), b256, 0, stream>>>(z_a, stA, 256);
    bn_lrelu<<<dim3((NNODES * 256 + 255) / 256), b256, 0, stream>>>(z_a, stA, g_a, be_a, 256);

    // dense1 256->128 + BN + lrelu
    split_kernel<<<dim3((NNODES * 256 / 4 + 255) / 256), b256, 0, stream>>>(z_a, zah, zal, NNODES * 256 / 4);
    gemm_mfma<<<dim3(128 / 64, MT), b256, 0, stream>>>(zah, zal, w1h, w1l, b_1, z_1, NNODES, 128, 256);
    colstats<<<dim3(80), b256, 0, stream>>>(z_1, st1, 128);
    bn_lrelu<<<dim3((NNODES * 128 + 255) / 256), b256, 0, stream>>>(z_1, st1, g_1, be_1, 128);

    // dense2 128->64 + BN + lrelu
    split_kernel<<<dim3((NNODES * 128 / 4 + 255) / 256), b256, 0, stream>>>(z_1, z1h, z1l, NNODES * 128 / 4);
    gemm_mfma<<<dim3(64 / 64, MT), b256, 0, stream>>>(z1h, z1l, w2h, w2l, b_2, z_2, NNODES, 64, 128);
    colstats<<<dim3(80), b256, 0, stream>>>(z_2, st2, 64);
    bn_lrelu<<<dim3((NNODES * 64 + 255) / 256), b256, 0, stream>>>(z_2, st2, g_2, be_2, 64);

    // dense3 64->3
    dense3_kernel<<<dim3((NNODES + 255) / 256), b256, 0, stream>>>(z_2, w_3, b_3, y3);
    // pairwise distances
    dist_kernel<<<dim3((NNODES + 255) / 256, (NNODES + 63) / 64), b256, 0, stream>>>(y3, (float*)d_out);
}

// Round 3
// 436.605 us; speedup vs baseline: 1.2399x; 1.0048x over previous
//
#include <hip/hip_runtime.h>
#include <math.h>

#define NNODES 10000
#define NEDGES 320000
#define ETOT   (NEDGES + NNODES)
#define FINF   512
#define HD     512     // H*D
#define DHEAD  256

typedef __attribute__((ext_vector_type(8))) short bf16x8;
typedef __attribute__((ext_vector_type(4))) float f32x4;

__device__ __forceinline__ ushort f2bf(float f) {
    unsigned u = __builtin_bit_cast(unsigned, f);
    unsigned r = (u + 0x7FFFu + ((u >> 16) & 1u)) >> 16;
    return (ushort)r;
}
__device__ __forceinline__ float bf2f(ushort h) {
    unsigned u = ((unsigned)h) << 16;
    return __builtin_bit_cast(float, u);
}

// ---------------- fp32 -> bf16 hi/lo split (vectorized) ----------------
__global__ __launch_bounds__(256) void split_kernel(const float* __restrict__ x,
    ushort* __restrict__ hi, ushort* __restrict__ lo, int n4)
{
    int i = blockIdx.x * 256 + threadIdx.x;
    if (i >= n4) return;
    float4 v = ((const float4*)x)[i];
    ushort4 h, l;
    h.x = f2bf(v.x); l.x = f2bf(v.x - bf2f(h.x));
    h.y = f2bf(v.y); l.y = f2bf(v.y - bf2f(h.y));
    h.z = f2bf(v.z); l.z = f2bf(v.z - bf2f(h.z));
    h.w = f2bf(v.w); l.w = f2bf(v.w - bf2f(h.w));
    ((ushort4*)hi)[i] = h;
    ((ushort4*)lo)[i] = l;
}

// ---------------- weight transpose + hi/lo split: w[K][N] -> t[N][K] ----------------
__global__ __launch_bounds__(256) void wsplit_kernel(const float* __restrict__ w,
    ushort* __restrict__ th, ushort* __restrict__ tl, int K, int N)
{
    int idx = blockIdx.x * 256 + threadIdx.x;
    if (idx >= K * N) return;
    int n = idx / K, k = idx - n * K;
    float v = w[(size_t)k * N + n];
    ushort h = f2bf(v);
    th[idx] = h;
    tl[idx] = f2bf(v - bf2f(h));
}

// ---------------- 128xBN bf16-MFMA GEMM, hi/lo split: C = A @ Bt^T (+bias) ----------------
// A: Ah/Al [M][K] bf16;  B: Bh/Bl [N][K] bf16 (pre-transposed). BK=32.
// 4 waves 2x2; wave tile 64 x (BN/2); frags MR=4 x NR.
template<int BN, int NR>
__global__ __launch_bounds__(256) void gemm_big(
    const ushort* __restrict__ Ah, const ushort* __restrict__ Al,
    const ushort* __restrict__ Bh, const ushort* __restrict__ Bl,
    const float* __restrict__ bias, float* __restrict__ C,
    int M, int N, int K)
{
    constexpr int BM = 128;
    constexpr int MR = 4;
    __shared__ ushort sAh[BM][40], sAl[BM][40];   // row stride 80B -> 2-way banks (free)
    __shared__ ushort sBh[BN][40], sBl[BN][40];
    int tid = threadIdx.x;
    int lane = tid & 63, wave = tid >> 6;
    int wr = wave >> 1, wc = wave & 1;
    int bm = blockIdx.y * BM, bn = blockIdx.x * BN;
    int mrow = lane & 15, kb = lane >> 4;

    // staging slots: (row, kc) ; thread t -> A slots (t>>2, t&3) and (+64 rows)
    int ar0 = tid >> 2, akc = tid & 3;
    int arow0 = bm + ar0, arow1 = arow0 + 64;
    size_t aoff0 = (size_t)(arow0 < M ? arow0 : M - 1) * K + akc * 8;
    size_t aoff1 = (size_t)(arow1 < M ? arow1 : M - 1) * K + akc * 8;
    size_t boff0 = (size_t)(bn + (tid >> 2)) * K + akc * 8;
    size_t boff1 = boff0 + (size_t)64 * K;        // only used when BN==128

    f32x4 acc[MR][NR];
    #pragma unroll
    for (int i = 0; i < MR; ++i)
        #pragma unroll
        for (int j = 0; j < NR; ++j)
            acc[i][j] = (f32x4){0.f, 0.f, 0.f, 0.f};

    for (int k0 = 0; k0 < K; k0 += 32) {
        int4 vah0 = *(const int4*)(Ah + aoff0 + k0);
        int4 vah1 = *(const int4*)(Ah + aoff1 + k0);
        int4 val0 = *(const int4*)(Al + aoff0 + k0);
        int4 val1 = *(const int4*)(Al + aoff1 + k0);
        int4 vbh0 = *(const int4*)(Bh + boff0 + k0);
        int4 vbl0 = *(const int4*)(Bl + boff0 + k0);
        int4 vbh1, vbl1;
        if constexpr (BN == 128) {
            vbh1 = *(const int4*)(Bh + boff1 + k0);
            vbl1 = *(const int4*)(Bl + boff1 + k0);
        }
        __syncthreads();   // frag reads of previous iter done
        *(int4*)&sAh[ar0][akc * 8]      = vah0;
        *(int4*)&sAh[ar0 + 64][akc * 8] = vah1;
        *(int4*)&sAl[ar0][akc * 8]      = val0;
        *(int4*)&sAl[ar0 + 64][akc * 8] = val1;
        *(int4*)&sBh[ar0][akc * 8]      = vbh0;
        *(int4*)&sBl[ar0][akc * 8]      = vbl0;
        if constexpr (BN == 128) {
            *(int4*)&sBh[ar0 + 64][akc * 8] = vbh1;
            *(int4*)&sBl[ar0 + 64][akc * 8] = vbl1;
        }
        __syncthreads();

        bf16x8 fah[MR], fal[MR], fbh[NR], fbl[NR];
        #pragma unroll
        for (int fi = 0; fi < MR; ++fi) {
            int r = wr * 64 + fi * 16 + mrow;
            fah[fi] = *(const bf16x8*)&sAh[r][kb * 8];
            fal[fi] = *(const bf16x8*)&sAl[r][kb * 8];
        }
        #pragma unroll
        for (int fj = 0; fj < NR; ++fj) {
            int c = wc * (BN / 2) + fj * 16 + mrow;
            fbh[fj] = *(const bf16x8*)&sBh[c][kb * 8];
            fbl[fj] = *(const bf16x8*)&sBl[c][kb * 8];
        }
        #pragma unroll
        for (int fi = 0; fi < MR; ++fi)
            #pragma unroll
            for (int fj = 0; fj < NR; ++fj) {
                acc[fi][fj] = __builtin_amdgcn_mfma_f32_16x16x32_bf16(fah[fi], fbh[fj], acc[fi][fj], 0, 0, 0);
                acc[fi][fj] = __builtin_amdgcn_mfma_f32_16x16x32_bf16(fah[fi], fbl[fj], acc[fi][fj], 0, 0, 0);
                acc[fi][fj] = __builtin_amdgcn_mfma_f32_16x16x32_bf16(fal[fi], fbh[fj], acc[fi][fj], 0, 0, 0);
            }
    }

    #pragma unroll
    for (int fi = 0; fi < MR; ++fi) {
        int crow0 = bm + wr * 64 + fi * 16 + (lane >> 4) * 4;
        #pragma unroll
        for (int fj = 0; fj < NR; ++fj) {
            int ccol = bn + wc * (BN / 2) + fj * 16 + (lane & 15);
            float bv = bias ? bias[ccol] : 0.f;
            #pragma unroll
            for (int r = 0; r < 4; ++r) {
                int row = crow0 + r;
                if (row < M) C[(size_t)row * N + ccol] = acc[fi][fj][r] + bv;
            }
        }
    }
}

// ---------------- attention coefficients a_src/a_dst [N,2] ----------------
__global__ __launch_bounds__(64) void attn_coef(const float* __restrict__ h,
    const float* __restrict__ att_s, const float* __restrict__ att_d,
    float* __restrict__ a_src, float* __restrict__ a_dst)
{
    int n = blockIdx.x, lane = threadIdx.x;
    const float* hr = h + (size_t)n * HD;
    float s0 = 0, s1 = 0, d0 = 0, d1 = 0;
    for (int j = lane; j < DHEAD; j += 64) {
        float v0 = hr[j], v1 = hr[DHEAD + j];
        s0 = fmaf(v0, att_s[j], s0);
        s1 = fmaf(v1, att_s[DHEAD + j], s1);
        d0 = fmaf(v0, att_d[j], d0);
        d1 = fmaf(v1, att_d[DHEAD + j], d1);
    }
    #pragma unroll
    for (int off = 32; off > 0; off >>= 1) {
        s0 += __shfl_down(s0, off);
        s1 += __shfl_down(s1, off);
        d0 += __shfl_down(d0, off);
        d1 += __shfl_down(d1, off);
    }
    if (lane == 0) {
        a_src[2 * n] = s0; a_src[2 * n + 1] = s1;
        a_dst[2 * n] = d0; a_dst[2 * n + 1] = d1;
    }
}

// ---------------- degree histogram over dst (incl. self-loops) ----------------
__global__ __launch_bounds__(256) void hist_kernel(const int* __restrict__ ei, int* __restrict__ deg)
{
    int e = blockIdx.x * 256 + threadIdx.x;
    if (e >= ETOT) return;
    int d = (e < NEDGES) ? ei[NEDGES + e] : (e - NEDGES);
    atomicAdd(&deg[d], 1);
}

// ---------------- single-block exclusive scan of deg -> row_start ----------------
__global__ __launch_bounds__(256) void scan_kernel(const int* __restrict__ deg, int* __restrict__ rowst)
{
    __shared__ int part[256];
    int t = threadIdx.x;
    const int chunk = (NNODES + 255) / 256;
    int base = t * chunk;
    int s = 0;
    for (int i = 0; i < chunk; ++i) {
        int n = base + i;
        if (n < NNODES) s += deg[n];
    }
    part[t] = s;
    __syncthreads();
    for (int off = 1; off < 256; off <<= 1) {
        int v = 0;
        if (t >= off) v = part[t - off];
        __syncthreads();
        if (t >= off) part[t] += v;
        __syncthreads();
    }
    int run = (t == 0) ? 0 : part[t - 1];
    for (int i = 0; i < chunk; ++i) {
        int n = base + i;
        if (n < NNODES) { rowst[n] = run; run += deg[n]; }
    }
}

// ---------------- scatter edges into CSR slots; precompute p = exp(lrelu(e)) ----------------
__global__ __launch_bounds__(256) void scatter_kernel(const int* __restrict__ ei,
    const float* __restrict__ a_src, const float* __restrict__ a_dst,
    const int* __restrict__ rowst, int* __restrict__ cnt,
    int* __restrict__ esrc, float* __restrict__ p0, float* __restrict__ p1)
{
    int e = blockIdx.x * 256 + threadIdx.x;
    if (e >= ETOT) return;
    int s, d;
    if (e < NEDGES) { s = ei[e]; d = ei[NEDGES + e]; } else { s = d = e - NEDGES; }
    int pos = rowst[d] + atomicAdd(&cnt[d], 1);
    esrc[pos] = s;
    float e0 = a_src[2 * s] + a_dst[2 * d];
    e0 = (e0 > 0.f) ? e0 : 0.2f * e0;
    float e1 = a_src[2 * s + 1] + a_dst[2 * d + 1];
    e1 = (e1 > 0.f) ? e1 : 0.2f * e1;
    p0[pos] = expf(e0);
    p1[pos] = expf(e1);
}

// ---------------- per-node aggregation -> lrelu -> bf16 hi/lo split ----------------
// 128 threads: thread t owns features [4t,4t+4); t<64 = head0 (p0), t>=64 = head1 (p1).
__global__ __launch_bounds__(128) void aggregate_kernel(const float* __restrict__ h,
    const int* __restrict__ rowst, const int* __restrict__ deg, const int* __restrict__ esrc,
    const float* __restrict__ p0, const float* __restrict__ p1,
    const float* __restrict__ b_conv, ushort* __restrict__ yh, ushort* __restrict__ yl)
{
    int n = blockIdx.x, t = threadIdx.x;
    int s = rowst[n], len = deg[n];
    const float* pp = (t < 64) ? p0 : p1;
    float4 acc = {0.f, 0.f, 0.f, 0.f};
    float den = 0.f;
    for (int k = 0; k < len; ++k) {
        int src = esrc[s + k];
        float q = pp[s + k];
        float4 hv = *(const float4*)(h + (size_t)src * HD + t * 4);
        acc.x = fmaf(q, hv.x, acc.x);
        acc.y = fmaf(q, hv.y, acc.y);
        acc.z = fmaf(q, hv.z, acc.z);
        acc.w = fmaf(q, hv.w, acc.w);
        den += q;
    }
    float4 bc = *(const float4*)(b_conv + t * 4);
    float inv = 1.f / den;
    float o[4] = { acc.x * inv + bc.x, acc.y * inv + bc.y,
                   acc.z * inv + bc.z, acc.w * inv + bc.w };
    ushort4 hq, lq;
    float v;
    v = (o[0] > 0.f) ? o[0] : 0.01f * o[0]; hq.x = f2bf(v); lq.x = f2bf(v - bf2f(hq.x));
    v = (o[1] > 0.f) ? o[1] : 0.01f * o[1]; hq.y = f2bf(v); lq.y = f2bf(v - bf2f(hq.y));
    v = (o[2] > 0.f) ? o[2] : 0.01f * o[2]; hq.z = f2bf(v); lq.z = f2bf(v - bf2f(hq.z));
    v = (o[3] > 0.f) ? o[3] : 0.01f * o[3]; hq.w = f2bf(v); lq.w = f2bf(v - bf2f(hq.w));
    ((ushort4*)(yh + (size_t)n * HD))[t] = hq;
    ((ushort4*)(yl + (size_t)n * HD))[t] = lq;
}

// ---------------- column sums + sum of squares (for BN batch stats) ----------------
__global__ __launch_bounds__(256) void colstats(const float* __restrict__ z, float* __restrict__ sums, int C)
{
    int t = threadIdx.x;
    int c = t & (C - 1);
    int rl = t / C;
    int rpi = 256 / C;
    float s = 0, s2 = 0;
    for (int r = blockIdx.x * rpi + rl; r < NNODES; r += gridDim.x * rpi) {
        float v = z[(size_t)r * C + c];
        s += v;
        s2 = fmaf(v, v, s2);
    }
    __shared__ float sh[256], sh2[256];
    sh[t] = s; sh2[t] = s2;
    __syncthreads();
    for (int off = 128; off >= C; off >>= 1) {
        if (t < off) { sh[t] += sh[t + off]; sh2[t] += sh2[t + off]; }
        __syncthreads();
    }
    if (t < C) {
        atomicAdd(&sums[c], sh[t]);
        atomicAdd(&sums[C + c], sh2[t]);
    }
}

// ---------------- BN + lrelu -> bf16 hi/lo split (for next GEMM's A operand) ----------------
__global__ __launch_bounds__(256) void bn_split(const float* __restrict__ z, const float* __restrict__ sums,
    const float* __restrict__ g, const float* __restrict__ beta,
    ushort* __restrict__ hi, ushort* __restrict__ lo, int C)
{
    int i = blockIdx.x * 256 + threadIdx.x;
    if (i >= NNODES * C / 4) return;
    int c0 = (i * 4) & (C - 1);
    float4 zv = ((const float4*)z)[i];
    float o[4] = {zv.x, zv.y, zv.z, zv.w};
    ushort4 hq, lq;
    ushort* hp = (ushort*)&hq;
    ushort* lp = (ushort*)&lq;
    #pragma unroll
    for (int j = 0; j < 4; ++j) {
        int c = c0 + j;
        float m = sums[c] * (1.f / NNODES);
        float vv = sums[C + c] * (1.f / NNODES) - m * m;
        float r = rsqrtf(vv + 1e-5f);
        float xv = g[c] * (o[j] - m) * r + beta[c];
        xv = (xv > 0.f) ? xv : 0.01f * xv;
        hp[j] = f2bf(xv);
        lp[j] = f2bf(xv - bf2f(hp[j]));
    }
    ((ushort4*)hi)[i] = hq;
    ((ushort4*)lo)[i] = lq;
}

// ---------------- BN + lrelu, f32 out (layer 2, feeds dense3) ----------------
__global__ __launch_bounds__(256) void bn_lrelu(float* __restrict__ z, const float* __restrict__ sums,
    const float* __restrict__ g, const float* __restrict__ beta, int C)
{
    int idx = blockIdx.x * 256 + threadIdx.x;
    if (idx >= NNODES * C) return;
    int c = idx & (C - 1);
    float m = sums[c] * (1.f / NNODES);
    float v = sums[C + c] * (1.f / NNODES) - m * m;
    float r = rsqrtf(v + 1e-5f);
    float xv = z[idx];
    xv = g[c] * (xv - m) * r + beta[c];
    z[idx] = (xv > 0.f) ? xv : 0.01f * xv;
}

// ---------------- final dense 64 -> 3 ----------------
__global__ __launch_bounds__(256) void dense3_kernel(const float* __restrict__ z2,
    const float* __restrict__ w3, const float* __restrict__ b3, float* __restrict__ y3)
{
    int n = blockIdx.x * 256 + threadIdx.x;
    if (n >= NNODES) return;
    float o0 = b3[0], o1 = b3[1], o2 = b3[2];
    const float* zr = z2 + (size_t)n * 64;
    #pragma unroll
    for (int j = 0; j < 64; ++j) {
        float v = zr[j];
        o0 = fmaf(v, w3[3 * j],     o0);
        o1 = fmaf(v, w3[3 * j + 1], o1);
        o2 = fmaf(v, w3[3 * j + 2], o2);
    }
    y3[3 * n] = o0; y3[3 * n + 1] = o1; y3[3 * n + 2] = o2;
}

// ---------------- pairwise euclidean distances [N,N] ----------------
__global__ __launch_bounds__(256) void dist_kernel(const float* __restrict__ y3, float* __restrict__ out)
{
    int j = blockIdx.x * 256 + threadIdx.x;
    int i0 = blockIdx.y * 64;
    bool jv = (j < NNODES);
    float xj = 0, yj = 0, zj = 0;
    if (jv) { xj = y3[3 * j]; yj = y3[3 * j + 1]; zj = y3[3 * j + 2]; }
    int iend = (i0 + 64 < NNODES) ? (i0 + 64) : NNODES;
    for (int i = i0; i < iend; ++i) {
        float xi = y3[3 * i], yi = y3[3 * i + 1], zi = y3[3 * i + 2];
        if (jv) {
            float dx = xi - xj, dy = yi - yj, dz = zi - zj;
            float d2 = fmaf(dx, dx, fmaf(dy, dy, dz * dz));
            out[(size_t)i * NNODES + j] = (d2 > 1e-12f) ? sqrtf(d2) : 0.f;
        }
    }
}

extern "C" void kernel_launch(void* const* d_in, const int* in_sizes, int n_in,
                              void* d_out, int out_size, void* d_ws, size_t ws_size,
                              hipStream_t stream)
{
    (void)in_sizes; (void)n_in; (void)out_size; (void)ws_size;
    const float* x      = (const float*)d_in[0];
    const int*   ei     = (const int*)  d_in[1];
    const float* w_conv = (const float*)d_in[2];
    const float* att_s  = (const float*)d_in[3];
    const float* att_d  = (const float*)d_in[4];
    const float* b_conv = (const float*)d_in[5];
    const float* w_a  = (const float*)d_in[6];
    const float* b_a  = (const float*)d_in[7];
    const float* g_a  = (const float*)d_in[8];
    const float* be_a = (const float*)d_in[9];
    const float* w_1  = (const float*)d_in[10];
    const float* b_1  = (const float*)d_in[11];
    const float* g_1  = (const float*)d_in[12];
    const float* be_1 = (const float*)d_in[13];
    const float* w_2  = (const float*)d_in[14];
    const float* b_2  = (const float*)d_in[15];
    const float* g_2  = (const float*)d_in[16];
    const float* be_2 = (const float*)d_in[17];
    const float* w_3  = (const float*)d_in[18];
    const float* b_3  = (const float*)d_in[19];

    char* ws = (char*)d_ws;
    size_t off = 0;
    auto take = [&](size_t bytes) {
        char* p = ws + off;
        off = (off + bytes + 255) & ~(size_t)255;
        return p;
    };
    float* h    = (float*)take((size_t)NNODES * HD * 4);
    float* z_a  = (float*)take((size_t)NNODES * 256 * 4);
    float* z_1  = (float*)take((size_t)NNODES * 128 * 4);
    float* z_2  = (float*)take((size_t)NNODES * 64 * 4);
    float* y3   = (float*)take((size_t)NNODES * 3 * 4);
    ushort* xh  = (ushort*)take((size_t)NNODES * FINF * 2);
    ushort* xl  = (ushort*)take((size_t)NNODES * FINF * 2);
    ushort* yh  = (ushort*)take((size_t)NNODES * HD * 2);
    ushort* yl  = (ushort*)take((size_t)NNODES * HD * 2);
    ushort* zah = (ushort*)take((size_t)NNODES * 256 * 2);
    ushort* zal = (ushort*)take((size_t)NNODES * 256 * 2);
    ushort* z1h = (ushort*)take((size_t)NNODES * 128 * 2);
    ushort* z1l = (ushort*)take((size_t)NNODES * 128 * 2);
    ushort* wch = (ushort*)take((size_t)512 * 512 * 2);
    ushort* wcl = (ushort*)take((size_t)512 * 512 * 2);
    ushort* wah = (ushort*)take((size_t)256 * 512 * 2);
    ushort* wal = (ushort*)take((size_t)256 * 512 * 2);
    ushort* w1h = (ushort*)take((size_t)128 * 256 * 2);
    ushort* w1l = (ushort*)take((size_t)128 * 256 * 2);
    ushort* w2h = (ushort*)take((size_t)64 * 128 * 2);
    ushort* w2l = (ushort*)take((size_t)64 * 128 * 2);
    float* a_src= (float*)take((size_t)NNODES * 2 * 4);
    float* a_dst= (float*)take((size_t)NNODES * 2 * 4);
    int*   rowst= (int*)  take((size_t)NNODES * 4);
    int*   esrc = (int*)  take((size_t)ETOT * 4);
    float* p0   = (float*)take((size_t)ETOT * 4);
    float* p1   = (float*)take((size_t)ETOT * 4);
    char*  zblk = take(40000 + 40000 + 2048 + 1024 + 512);
    int*   deg  = (int*)(zblk);
    int*   cnt  = (int*)(zblk + 40000);
    float* stA  = (float*)(zblk + 80000);
    float* st1  = (float*)(zblk + 82048);
    float* st2  = (float*)(zblk + 83072);

    hipMemsetAsync(zblk, 0, 40000 + 40000 + 2048 + 1024 + 512, stream);

    dim3 b256(256), b64(64), b128(128);
    const int MT = (NNODES + 127) / 128;   // 79 M-tiles

    // prep: split x, transpose+split all weights
    split_kernel<<<dim3((NNODES * FINF / 4 + 255) / 256), b256, 0, stream>>>(x, xh, xl, NNODES * FINF / 4);
    wsplit_kernel<<<dim3((512 * 512 + 255) / 256), b256, 0, stream>>>(w_conv, wch, wcl, 512, 512);
    wsplit_kernel<<<dim3((512 * 256 + 255) / 256), b256, 0, stream>>>(w_a, wah, wal, 512, 256);
    wsplit_kernel<<<dim3((256 * 128 + 255) / 256), b256, 0, stream>>>(w_1, w1h, w1l, 256, 128);
    wsplit_kernel<<<dim3((128 * 64 + 255) / 256), b256, 0, stream>>>(w_2, w2h, w2l, 128, 64);

    // h = x @ w_conv  (MFMA, 128x128 tiles)
    gemm_big<128, 4><<<dim3(HD / 128, MT), b256, 0, stream>>>(xh, xl, wch, wcl, nullptr, h, NNODES, HD, FINF);

    attn_coef<<<dim3(NNODES), b64, 0, stream>>>(h, att_s, att_d, a_src, a_dst);
    hist_kernel<<<dim3((ETOT + 255) / 256), b256, 0, stream>>>(ei, deg);
    scan_kernel<<<dim3(1), b256, 0, stream>>>(deg, rowst);
    scatter_kernel<<<dim3((ETOT + 255) / 256), b256, 0, stream>>>(ei, a_src, a_dst, rowst, cnt, esrc, p0, p1);
    aggregate_kernel<<<dim3(NNODES), b128, 0, stream>>>(h, rowst, deg, esrc, p0, p1, b_conv, yh, yl);

    // densea 512->256 + BN + lrelu (+split)
    gemm_big<128, 4><<<dim3(256 / 128, MT), b256, 0, stream>>>(yh, yl, wah, wal, b_a, z_a, NNODES, 256, 512);
    colstats<<<dim3(80), b256, 0, stream>>>(z_a, stA, 256);
    bn_split<<<dim3((NNODES * 256 / 4 + 255) / 256), b256, 0, stream>>>(z_a, stA, g_a, be_a, zah, zal, 256);

    // dense1 256->128 + BN + lrelu (+split)
    gemm_big<64, 2><<<dim3(128 / 64, MT), b256, 0, stream>>>(zah, zal, w1h, w1l, b_1, z_1, NNODES, 128, 256);
    colstats<<<dim3(80), b256, 0, stream>>>(z_1, st1, 128);
    bn_split<<<dim3((NNODES * 128 / 4 + 255) / 256), b256, 0, stream>>>(z_1, st1, g_1, be_1, z1h, z1l, 128);

    // dense2 128->64 + BN + lrelu (f32)
    gemm_big<64, 2><<<dim3(64 / 64, MT), b256, 0, stream>>>(z1h, z1l, w2h, w2l, b_2, z_2, NNODES, 64, 128);
    colstats<<<dim3(80), b256, 0, stream>>>(z_2, st2, 64);
    bn_lrelu<<<dim3((NNODES * 64 + 255) / 256), b256, 0, stream>>>(z_2, st2, g_2, be_2, 64);

    // dense3 64->3
    dense3_kernel<<<dim3((NNODES + 255) / 256), b256, 0, stream>>>(z_2, w_3, b_3, y3);
    // pairwise distances
    dist_kernel<<<dim3((NNODES + 255) / 256, (NNODES + 63) / 64), b256, 0, stream>>>(y3, (float*)d_out);
}

// Round 4
// 357.098 us; speedup vs baseline: 1.5159x; 1.2226x over previous
//
#include <hip/hip_runtime.h>
#include <math.h>

#define NNODES 10000
#define NEDGES 320000
#define ETOT   (NEDGES + NNODES)
#define FINF   512
#define HD     512     // H*D
#define DHEAD  256

typedef __attribute__((ext_vector_type(8))) short bf16x8;
typedef __attribute__((ext_vector_type(4))) float f32x4;

__device__ __forceinline__ ushort f2bf(float f) {
    unsigned u = __builtin_bit_cast(unsigned, f);
    unsigned r = (u + 0x7FFFu + ((u >> 16) & 1u)) >> 16;
    return (ushort)r;
}
__device__ __forceinline__ float bf2f(ushort h) {
    unsigned u = ((unsigned)h) << 16;
    return __builtin_bit_cast(float, u);
}

// ---------------- fused prep: split x (float4) + transpose-split 4 weights ----------------
#define XW4 1280000                      // NNODES*FINF/4
#define PE1 (XW4 + 512 * 512)            // w_conv
#define PE2 (PE1 + 256 * 512)            // w_a
#define PE3 (PE2 + 128 * 256)            // w_1
#define PE4 (PE3 + 64 * 128)             // w_2
__global__ __launch_bounds__(256) void prep_kernel(
    const float* __restrict__ x, ushort* __restrict__ xh, ushort* __restrict__ xl,
    const float* __restrict__ wc, ushort* __restrict__ wch, ushort* __restrict__ wcl,
    const float* __restrict__ wa, ushort* __restrict__ wah, ushort* __restrict__ wal,
    const float* __restrict__ w1, ushort* __restrict__ w1h, ushort* __restrict__ w1l,
    const float* __restrict__ w2, ushort* __restrict__ w2h, ushort* __restrict__ w2l)
{
    int idx = blockIdx.x * 256 + threadIdx.x;
    if (idx < XW4) {
        float4 v = ((const float4*)x)[idx];
        ushort4 h, l;
        h.x = f2bf(v.x); l.x = f2bf(v.x - bf2f(h.x));
        h.y = f2bf(v.y); l.y = f2bf(v.y - bf2f(h.y));
        h.z = f2bf(v.z); l.z = f2bf(v.z - bf2f(h.z));
        h.w = f2bf(v.w); l.w = f2bf(v.w - bf2f(h.w));
        ((ushort4*)xh)[idx] = h;
        ((ushort4*)xl)[idx] = l;
        return;
    }
    float v; ushort* th; ushort* tl; int i;
    if (idx < PE1) {            // w_conv [512][512] -> [512][512]^T
        i = idx - XW4; int n = i >> 9, k = i & 511;
        v = wc[(size_t)k * 512 + n]; th = wch; tl = wcl;
    } else if (idx < PE2) {     // w_a [512][256] -> [256][512]
        i = idx - PE1; int n = i >> 9, k = i & 511;
        v = wa[(size_t)k * 256 + n]; th = wah; tl = wal;
    } else if (idx < PE3) {     // w_1 [256][128] -> [128][256]
        i = idx - PE2; int n = i >> 8, k = i & 255;
        v = w1[(size_t)k * 128 + n]; th = w1h; tl = w1l;
    } else if (idx < PE4) {     // w_2 [128][64] -> [64][128]
        i = idx - PE3; int n = i >> 7, k = i & 127;
        v = w2[(size_t)k * 64 + n]; th = w2h; tl = w2l;
    } else return;
    ushort h = f2bf(v);
    th[i] = h;
    tl[i] = f2bf(v - bf2f(h));
}

// ---------------- bf16-MFMA GEMM (hi/lo), optional fused attn / BN-stats epilogue ----------
// A: Ah/Al [M][K] bf16; B: Bh/Bl [N][K] bf16 (pre-transposed). BK=32, BM=64.
// 4 waves 2x2; wave tile 32 x (BN/2); frags MR=2 x NR=BN/32.
template<int BN, bool ATTN, bool STATS>
__global__ __launch_bounds__(256) void gemm_fused(
    const ushort* __restrict__ Ah, const ushort* __restrict__ Al,
    const ushort* __restrict__ Bh, const ushort* __restrict__ Bl,
    float* __restrict__ C, int M, int N, int K,
    const float* __restrict__ att_s, const float* __restrict__ att_d,
    float* __restrict__ a_src, float* __restrict__ a_dst,
    float* __restrict__ stats, int Cst)
{
    constexpr int BM = 64;
    constexpr int MR = 2, NR = BN / 32;
    __shared__ ushort sAh[BM][40], sAl[BM][40];   // 80B row stride
    __shared__ ushort sBh[BN][40], sBl[BN][40];
    int tid = threadIdx.x;
    int lane = tid & 63, wave = tid >> 6;
    int wr = wave >> 1, wc = wave & 1;
    int bm = blockIdx.y * BM, bn = blockIdx.x * BN;
    int mrow = lane & 15, kb = lane >> 4;

    int ar = tid >> 2, akc = tid & 3;
    int arow = bm + ar;
    bool aval = arow < M;
    size_t aoff = (size_t)(aval ? arow : 0) * K + akc * 8;
    int br, bkc;
    if constexpr (BN == 128) { br = tid >> 1; bkc = (tid & 1) * 2; }
    else { br = tid >> 2; bkc = tid & 3; }
    size_t boff = (size_t)(bn + br) * K + bkc * 8;

    f32x4 acc[MR][NR];
    #pragma unroll
    for (int i = 0; i < MR; ++i)
        #pragma unroll
        for (int j = 0; j < NR; ++j)
            acc[i][j] = (f32x4){0.f, 0.f, 0.f, 0.f};

    for (int k0 = 0; k0 < K; k0 += 32) {
        int4 vah = {0,0,0,0}, val4 = {0,0,0,0};
        if (aval) {
            vah  = *(const int4*)(Ah + aoff + k0);
            val4 = *(const int4*)(Al + aoff + k0);
        }
        int4 vbh0 = *(const int4*)(Bh + boff + k0);
        int4 vbl0 = *(const int4*)(Bl + boff + k0);
        int4 vbh1, vbl1;
        if constexpr (BN == 128) {
            vbh1 = *(const int4*)(Bh + boff + k0 + 8);
            vbl1 = *(const int4*)(Bl + boff + k0 + 8);
        }
        __syncthreads();
        *(int4*)&sAh[ar][akc * 8] = vah;
        *(int4*)&sAl[ar][akc * 8] = val4;
        *(int4*)&sBh[br][bkc * 8] = vbh0;
        *(int4*)&sBl[br][bkc * 8] = vbl0;
        if constexpr (BN == 128) {
            *(int4*)&sBh[br][(bkc + 1) * 8] = vbh1;
            *(int4*)&sBl[br][(bkc + 1) * 8] = vbl1;
        }
        __syncthreads();

        bf16x8 fah[MR], fal[MR], fbh[NR], fbl[NR];
        #pragma unroll
        for (int fi = 0; fi < MR; ++fi) {
            int r = wr * 32 + fi * 16 + mrow;
            fah[fi] = *(const bf16x8*)&sAh[r][kb * 8];
            fal[fi] = *(const bf16x8*)&sAl[r][kb * 8];
        }
        #pragma unroll
        for (int fj = 0; fj < NR; ++fj) {
            int c = wc * (BN / 2) + fj * 16 + mrow;
            fbh[fj] = *(const bf16x8*)&sBh[c][kb * 8];
            fbl[fj] = *(const bf16x8*)&sBl[c][kb * 8];
        }
        #pragma unroll
        for (int fi = 0; fi < MR; ++fi)
            #pragma unroll
            for (int fj = 0; fj < NR; ++fj) {
                acc[fi][fj] = __builtin_amdgcn_mfma_f32_16x16x32_bf16(fah[fi], fbh[fj], acc[fi][fj], 0, 0, 0);
                acc[fi][fj] = __builtin_amdgcn_mfma_f32_16x16x32_bf16(fah[fi], fbl[fj], acc[fi][fj], 0, 0, 0);
                acc[fi][fj] = __builtin_amdgcn_mfma_f32_16x16x32_bf16(fal[fi], fbh[fj], acc[fi][fj], 0, 0, 0);
            }
    }

    // C write: row = bm + wr*32 + fi*16 + (lane>>4)*4 + r ; col = bn + wc*(BN/2) + fj*16 + mrow
    #pragma unroll
    for (int fi = 0; fi < MR; ++fi) {
        int crow0 = bm + wr * 32 + fi * 16 + (lane >> 4) * 4;
        #pragma unroll
        for (int fj = 0; fj < NR; ++fj) {
            int ccol = bn + wc * (BN / 2) + fj * 16 + mrow;
            #pragma unroll
            for (int r = 0; r < 4; ++r) {
                int row = crow0 + r;
                if (row < M) C[(size_t)row * N + ccol] = acc[fi][fj][r];
            }
        }
    }

    if constexpr (ATTN) {
        // a_src[row,hd] += sum_cols h*att_s ; block's cols all in head hd = bn>>8
        int hd = bn >> 8;
        float as_v[NR], ad_v[NR];
        #pragma unroll
        for (int fj = 0; fj < NR; ++fj) {
            int c = bn + wc * (BN / 2) + fj * 16 + mrow;
            as_v[fj] = att_s[c];
            ad_v[fj] = att_d[c];
        }
        #pragma unroll
        for (int fi = 0; fi < MR; ++fi)
            #pragma unroll
            for (int r = 0; r < 4; ++r) {
                float ss = 0.f, sd = 0.f;
                #pragma unroll
                for (int fj = 0; fj < NR; ++fj) {
                    float v = acc[fi][fj][r];
                    ss = fmaf(v, as_v[fj], ss);
                    sd = fmaf(v, ad_v[fj], sd);
                }
                #pragma unroll
                for (int off = 1; off < 16; off <<= 1) {
                    ss += __shfl_xor(ss, off);
                    sd += __shfl_xor(sd, off);
                }
                if (mrow == 0) {
                    int row = bm + wr * 32 + fi * 16 + (lane >> 4) * 4 + r;
                    if (row < M) {
                        atomicAdd(&a_src[2 * row + hd], ss);
                        atomicAdd(&a_dst[2 * row + hd], sd);
                    }
                }
            }
    }

    if constexpr (STATS) {
        // per-column sum & sumsq over this wave's 32 rows (rows>=M staged as 0)
        #pragma unroll
        for (int fj = 0; fj < NR; ++fj) {
            float s = 0.f, s2 = 0.f;
            #pragma unroll
            for (int fi = 0; fi < MR; ++fi)
                #pragma unroll
                for (int r = 0; r < 4; ++r) {
                    float v = acc[fi][fj][r];
                    s += v;
                    s2 = fmaf(v, v, s2);
                }
            s  += __shfl_xor(s, 16);  s  += __shfl_xor(s, 32);
            s2 += __shfl_xor(s2, 16); s2 += __shfl_xor(s2, 32);
            if (lane < 16) {
                int c = bn + wc * (BN / 2) + fj * 16 + lane;
                atomicAdd(&stats[c], s);
                atomicAdd(&stats[Cst + c], s2);
            }
        }
    }
}

// ---------------- degree histogram over dst (incl. self-loops) ----------------
__global__ __launch_bounds__(256) void hist_kernel(const int* __restrict__ ei, int* __restrict__ deg)
{
    int e = blockIdx.x * 256 + threadIdx.x;
    if (e >= ETOT) return;
    int d = (e < NEDGES) ? ei[NEDGES + e] : (e - NEDGES);
    atomicAdd(&deg[d], 1);
}

// ---------------- single-block exclusive scan of deg -> row_start ----------------
__global__ __launch_bounds__(256) void scan_kernel(const int* __restrict__ deg, int* __restrict__ rowst)
{
    __shared__ int part[256];
    int t = threadIdx.x;
    const int chunk = (NNODES + 255) / 256;
    int base = t * chunk;
    int s = 0;
    for (int i = 0; i < chunk; ++i) {
        int n = base + i;
        if (n < NNODES) s += deg[n];
    }
    part[t] = s;
    __syncthreads();
    for (int off = 1; off < 256; off <<= 1) {
        int v = 0;
        if (t >= off) v = part[t - off];
        __syncthreads();
        if (t >= off) part[t] += v;
        __syncthreads();
    }
    int run = (t == 0) ? 0 : part[t - 1];
    for (int i = 0; i < chunk; ++i) {
        int n = base + i;
        if (n < NNODES) { rowst[n] = run; run += deg[n]; }
    }
}

// ---------------- scatter edges into CSR slots; precompute p = exp(lrelu(e)) ----------------
__global__ __launch_bounds__(256) void scatter_kernel(const int* __restrict__ ei,
    const float* __restrict__ a_src, const float* __restrict__ a_dst,
    const int* __restrict__ rowst, int* __restrict__ cnt,
    int* __restrict__ esrc, float* __restrict__ p0, float* __restrict__ p1)
{
    int e = blockIdx.x * 256 + threadIdx.x;
    if (e >= ETOT) return;
    int s, d;
    if (e < NEDGES) { s = ei[e]; d = ei[NEDGES + e]; } else { s = d = e - NEDGES; }
    int pos = rowst[d] + atomicAdd(&cnt[d], 1);
    esrc[pos] = s;
    float e0 = a_src[2 * s] + a_dst[2 * d];
    e0 = (e0 > 0.f) ? e0 : 0.2f * e0;
    float e1 = a_src[2 * s + 1] + a_dst[2 * d + 1];
    e1 = (e1 > 0.f) ? e1 : 0.2f * e1;
    p0[pos] = expf(e0);
    p1[pos] = expf(e1);
}

// ---------------- per-node aggregation -> lrelu -> bf16 hi/lo split ----------------
__global__ __launch_bounds__(128) void aggregate_kernel(const float* __restrict__ h,
    const int* __restrict__ rowst, const int* __restrict__ deg, const int* __restrict__ esrc,
    const float* __restrict__ p0, const float* __restrict__ p1,
    const float* __restrict__ b_conv, ushort* __restrict__ yh, ushort* __restrict__ yl)
{
    int n = blockIdx.x, t = threadIdx.x;
    int s = rowst[n], len = deg[n];
    const float* pp = (t < 64) ? p0 : p1;
    float4 acc = {0.f, 0.f, 0.f, 0.f};
    float den = 0.f;
    for (int k = 0; k < len; ++k) {
        int src = esrc[s + k];
        float q = pp[s + k];
        float4 hv = *(const float4*)(h + (size_t)src * HD + t * 4);
        acc.x = fmaf(q, hv.x, acc.x);
        acc.y = fmaf(q, hv.y, acc.y);
        acc.z = fmaf(q, hv.z, acc.z);
        acc.w = fmaf(q, hv.w, acc.w);
        den += q;
    }
    float4 bc = *(const float4*)(b_conv + t * 4);
    float inv = 1.f / den;
    float o[4] = { acc.x * inv + bc.x, acc.y * inv + bc.y,
                   acc.z * inv + bc.z, acc.w * inv + bc.w };
    ushort4 hq, lq;
    float v;
    v = (o[0] > 0.f) ? o[0] : 0.01f * o[0]; hq.x = f2bf(v); lq.x = f2bf(v - bf2f(hq.x));
    v = (o[1] > 0.f) ? o[1] : 0.01f * o[1]; hq.y = f2bf(v); lq.y = f2bf(v - bf2f(hq.y));
    v = (o[2] > 0.f) ? o[2] : 0.01f * o[2]; hq.z = f2bf(v); lq.z = f2bf(v - bf2f(hq.z));
    v = (o[3] > 0.f) ? o[3] : 0.01f * o[3]; hq.w = f2bf(v); lq.w = f2bf(v - bf2f(hq.w));
    ((ushort4*)(yh + (size_t)n * HD))[t] = hq;
    ((ushort4*)(yl + (size_t)n * HD))[t] = lq;
}

// ---------------- BN + lrelu -> bf16 hi/lo split ----------------
__global__ __launch_bounds__(256) void bn_split(const float* __restrict__ z, const float* __restrict__ sums,
    const float* __restrict__ g, const float* __restrict__ beta,
    ushort* __restrict__ hi, ushort* __restrict__ lo, int C)
{
    int i = blockIdx.x * 256 + threadIdx.x;
    if (i >= NNODES * C / 4) return;
    int c0 = (i * 4) & (C - 1);
    float4 zv = ((const float4*)z)[i];
    float o[4] = {zv.x, zv.y, zv.z, zv.w};
    ushort4 hq, lq;
    ushort* hp = (ushort*)&hq;
    ushort* lp = (ushort*)&lq;
    #pragma unroll
    for (int j = 0; j < 4; ++j) {
        int c = c0 + j;
        float m = sums[c] * (1.f / NNODES);
        float vv = sums[C + c] * (1.f / NNODES) - m * m;
        float r = rsqrtf(vv + 1e-5f);
        float xv = g[c] * (o[j] - m) * r + beta[c];
        xv = (xv > 0.f) ? xv : 0.01f * xv;
        hp[j] = f2bf(xv);
        lp[j] = f2bf(xv - bf2f(hp[j]));
    }
    ((ushort4*)hi)[i] = hq;
    ((ushort4*)lo)[i] = lq;
}

// ---------------- BN(64) + lrelu + dense3 fused -> y3 ----------------
__global__ __launch_bounds__(256) void bn_dense3(const float* __restrict__ z2,
    const float* __restrict__ st, const float* __restrict__ g, const float* __restrict__ beta,
    const float* __restrict__ w3, const float* __restrict__ b3, float* __restrict__ y3)
{
    __shared__ float wsm[192], msm[64], rsm[64], gsm[64], bsm[64];
    int t = threadIdx.x;
    if (t < 192) wsm[t] = w3[t];
    if (t < 64) {
        float m = st[t] * (1.f / NNODES);
        float v = st[64 + t] * (1.f / NNODES) - m * m;
        msm[t] = m; rsm[t] = rsqrtf(v + 1e-5f);
        gsm[t] = g[t]; bsm[t] = beta[t];
    }
    __syncthreads();
    int n = blockIdx.x * 256 + t;
    if (n >= NNODES) return;
    const float* zr = z2 + (size_t)n * 64;
    float o0 = b3[0], o1 = b3[1], o2 = b3[2];
    #pragma unroll
    for (int c = 0; c < 64; ++c) {
        float xv = zr[c];
        xv = gsm[c] * (xv - msm[c]) * rsm[c] + bsm[c];
        xv = (xv > 0.f) ? xv : 0.01f * xv;
        o0 = fmaf(xv, wsm[3 * c],     o0);
        o1 = fmaf(xv, wsm[3 * c + 1], o1);
        o2 = fmaf(xv, wsm[3 * c + 2], o2);
    }
    y3[3 * n] = o0; y3[3 * n + 1] = o1; y3[3 * n + 2] = o2;
}

// ---------------- pairwise euclidean distances [N,N] ----------------
__global__ __launch_bounds__(256) void dist_kernel(const float* __restrict__ y3, float* __restrict__ out)
{
    int j = blockIdx.x * 256 + threadIdx.x;
    int i0 = blockIdx.y * 64;
    bool jv = (j < NNODES);
    float xj = 0, yj = 0, zj = 0;
    if (jv) { xj = y3[3 * j]; yj = y3[3 * j + 1]; zj = y3[3 * j + 2]; }
    int iend = (i0 + 64 < NNODES) ? (i0 + 64) : NNODES;
    for (int i = i0; i < iend; ++i) {
        float xi = y3[3 * i], yi = y3[3 * i + 1], zi = y3[3 * i + 2];
        if (jv) {
            float dx = xi - xj, dy = yi - yj, dz = zi - zj;
            float d2 = fmaf(dx, dx, fmaf(dy, dy, dz * dz));
            out[(size_t)i * NNODES + j] = (d2 > 1e-12f) ? sqrtf(d2) : 0.f;
        }
    }
}

extern "C" void kernel_launch(void* const* d_in, const int* in_sizes, int n_in,
                              void* d_out, int out_size, void* d_ws, size_t ws_size,
                              hipStream_t stream)
{
    (void)in_sizes; (void)n_in; (void)out_size; (void)ws_size;
    const float* x      = (const float*)d_in[0];
    const int*   ei     = (const int*)  d_in[1];
    const float* w_conv = (const float*)d_in[2];
    const float* att_s  = (const float*)d_in[3];
    const float* att_d  = (const float*)d_in[4];
    const float* b_conv = (const float*)d_in[5];
    const float* w_a  = (const float*)d_in[6];
    const float* g_a  = (const float*)d_in[8];
    const float* be_a = (const float*)d_in[9];
    const float* w_1  = (const float*)d_in[10];
    const float* g_1  = (const float*)d_in[12];
    const float* be_1 = (const float*)d_in[13];
    const float* w_2  = (const float*)d_in[14];
    const float* g_2  = (const float*)d_in[16];
    const float* be_2 = (const float*)d_in[17];
    const float* w_3  = (const float*)d_in[18];
    const float* b_3  = (const float*)d_in[19];

    char* ws = (char*)d_ws;
    size_t off = 0;
    auto take = [&](size_t bytes) {
        char* p = ws + off;
        off = (off + bytes + 255) & ~(size_t)255;
        return p;
    };
    float* h    = (float*)take((size_t)NNODES * HD * 4);
    float* z_a  = (float*)take((size_t)NNODES * 256 * 4);
    float* z_1  = (float*)take((size_t)NNODES * 128 * 4);
    float* z_2  = (float*)take((size_t)NNODES * 64 * 4);
    float* y3   = (float*)take((size_t)NNODES * 3 * 4);
    ushort* xh  = (ushort*)take((size_t)NNODES * FINF * 2);
    ushort* xl  = (ushort*)take((size_t)NNODES * FINF * 2);
    ushort* yh  = (ushort*)take((size_t)NNODES * HD * 2);
    ushort* yl  = (ushort*)take((size_t)NNODES * HD * 2);
    ushort* zah = (ushort*)take((size_t)NNODES * 256 * 2);
    ushort* zal = (ushort*)take((size_t)NNODES * 256 * 2);
    ushort* z1h = (ushort*)take((size_t)NNODES * 128 * 2);
    ushort* z1l = (ushort*)take((size_t)NNODES * 128 * 2);
    ushort* wch = (ushort*)take((size_t)512 * 512 * 2);
    ushort* wcl = (ushort*)take((size_t)512 * 512 * 2);
    ushort* wah = (ushort*)take((size_t)256 * 512 * 2);
    ushort* wal = (ushort*)take((size_t)256 * 512 * 2);
    ushort* w1h = (ushort*)take((size_t)128 * 256 * 2);
    ushort* w1l = (ushort*)take((size_t)128 * 256 * 2);
    ushort* w2h = (ushort*)take((size_t)64 * 128 * 2);
    ushort* w2l = (ushort*)take((size_t)64 * 128 * 2);
    int*   rowst= (int*)  take((size_t)NNODES * 4);
    int*   esrc = (int*)  take((size_t)ETOT * 4);
    float* p0   = (float*)take((size_t)ETOT * 4);
    float* p1   = (float*)take((size_t)ETOT * 4);
    // zeroed block: deg, cnt, stats x3, a_src, a_dst
    const size_t ZB = 40000 + 40000 + 2048 + 1024 + 512 + 80000 + 80000;
    char*  zblk = take(ZB);
    int*   deg  = (int*)(zblk);
    int*   cnt  = (int*)(zblk + 40000);
    float* stA  = (float*)(zblk + 80000);
    float* st1  = (float*)(zblk + 82048);
    float* st2  = (float*)(zblk + 83072);
    float* a_src= (float*)(zblk + 83584);
    float* a_dst= (float*)(zblk + 163584);

    hipMemsetAsync(zblk, 0, ZB, stream);

    dim3 b256(256), b128(128);
    const int MT = (NNODES + 63) / 64;   // 157

    prep_kernel<<<dim3(PE4 / 256), b256, 0, stream>>>(x, xh, xl,
        w_conv, wch, wcl, w_a, wah, wal, w_1, w1h, w1l, w_2, w2h, w2l);

    // h = x @ w_conv, fused attn coefficients
    gemm_fused<128, true, false><<<dim3(HD / 128, MT), b256, 0, stream>>>(
        xh, xl, wch, wcl, h, NNODES, HD, FINF, att_s, att_d, a_src, a_dst, nullptr, 0);

    hist_kernel<<<dim3((ETOT + 255) / 256), b256, 0, stream>>>(ei, deg);
    scan_kernel<<<dim3(1), b256, 0, stream>>>(deg, rowst);
    scatter_kernel<<<dim3((ETOT + 255) / 256), b256, 0, stream>>>(ei, a_src, a_dst, rowst, cnt, esrc, p0, p1);
    aggregate_kernel<<<dim3(NNODES), b128, 0, stream>>>(h, rowst, deg, esrc, p0, p1, b_conv, yh, yl);

    // densea 512->256 (stats fused) + BN/lrelu/split
    gemm_fused<128, false, true><<<dim3(256 / 128, MT), b256, 0, stream>>>(
        yh, yl, wah, wal, z_a, NNODES, 256, 512, nullptr, nullptr, nullptr, nullptr, stA, 256);
    bn_split<<<dim3((NNODES * 256 / 4 + 255) / 256), b256, 0, stream>>>(z_a, stA, g_a, be_a, zah, zal, 256);

    // dense1 256->128 (stats fused) + BN/lrelu/split
    gemm_fused<64, false, true><<<dim3(128 / 64, MT), b256, 0, stream>>>(
        zah, zal, w1h, w1l, z_1, NNODES, 128, 256, nullptr, nullptr, nullptr, nullptr, st1, 128);
    bn_split<<<dim3((NNODES * 128 / 4 + 255) / 256), b256, 0, stream>>>(z_1, st1, g_1, be_1, z1h, z1l, 128);

    // dense2 128->64 (stats fused)
    gemm_fused<64, false, true><<<dim3(64 / 64, MT), b256, 0, stream>>>(
        z1h, z1l, w2h, w2l, z_2, NNODES, 64, 128, nullptr, nullptr, nullptr, nullptr, st2, 64);

    // BN + lrelu + dense3 fused
    bn_dense3<<<dim3((NNODES + 255) / 256), b256, 0, stream>>>(z_2, st2, g_2, be_2, w_3, b_3, y3);

    // pairwise distances
    dist_kernel<<<dim3((NNODES + 255) / 256, (NNODES + 63) / 64), b256, 0, stream>>>(y3, (float*)d_out);
}

// Round 6
// 327.457 us; speedup vs baseline: 1.6531x; 1.0905x over previous
//
#include <hip/hip_runtime.h>
#include <math.h>

#define NNODES 10000
#define NEDGES 320000
#define ETOT   (NEDGES + NNODES)
#define FINF   512
#define HD     512     // H*D
#define DHEAD  256

typedef __attribute__((ext_vector_type(8))) short bf16x8;
typedef __attribute__((ext_vector_type(4))) float f32x4;

__device__ __forceinline__ ushort f2bf(float f) {
    unsigned u = __builtin_bit_cast(unsigned, f);
    unsigned r = (u + 0x7FFFu + ((u >> 16) & 1u)) >> 16;
    return (ushort)r;
}
__device__ __forceinline__ float bf2f(ushort h) {
    unsigned u = ((unsigned)h) << 16;
    return __builtin_bit_cast(float, u);
}

// ---------------- fused prep: split x (float4) + transpose-split 4 weights ----------------
#define XW4 1280000                      // NNODES*FINF/4
#define PE1 (XW4 + 512 * 512)            // w_conv
#define PE2 (PE1 + 256 * 512)            // w_a
#define PE3 (PE2 + 128 * 256)            // w_1
#define PE4 (PE3 + 64 * 128)             // w_2
__global__ __launch_bounds__(256) void prep_kernel(
    const float* __restrict__ x, ushort* __restrict__ xh, ushort* __restrict__ xl,
    const float* __restrict__ wc, ushort* __restrict__ wch, ushort* __restrict__ wcl,
    const float* __restrict__ wa, ushort* __restrict__ wah, ushort* __restrict__ wal,
    const float* __restrict__ w1, ushort* __restrict__ w1h, ushort* __restrict__ w1l,
    const float* __restrict__ w2, ushort* __restrict__ w2h, ushort* __restrict__ w2l)
{
    int idx = blockIdx.x * 256 + threadIdx.x;
    if (idx < XW4) {
        float4 v = ((const float4*)x)[idx];
        ushort4 h, l;
        h.x = f2bf(v.x); l.x = f2bf(v.x - bf2f(h.x));
        h.y = f2bf(v.y); l.y = f2bf(v.y - bf2f(h.y));
        h.z = f2bf(v.z); l.z = f2bf(v.z - bf2f(h.z));
        h.w = f2bf(v.w); l.w = f2bf(v.w - bf2f(h.w));
        ((ushort4*)xh)[idx] = h;
        ((ushort4*)xl)[idx] = l;
        return;
    }
    float v; ushort* th; ushort* tl; int i;
    if (idx < PE1) {            // w_conv [512][512] -> [512][512]^T
        i = idx - XW4; int n = i >> 9, k = i & 511;
        v = wc[(size_t)k * 512 + n]; th = wch; tl = wcl;
    } else if (idx < PE2) {     // w_a [512][256] -> [256][512]
        i = idx - PE1; int n = i >> 9, k = i & 511;
        v = wa[(size_t)k * 256 + n]; th = wah; tl = wal;
    } else if (idx < PE3) {     // w_1 [256][128] -> [128][256]
        i = idx - PE2; int n = i >> 8, k = i & 255;
        v = w1[(size_t)k * 128 + n]; th = w1h; tl = w1l;
    } else if (idx < PE4) {     // w_2 [128][64] -> [64][128]
        i = idx - PE3; int n = i >> 7, k = i & 127;
        v = w2[(size_t)k * 64 + n]; th = w2h; tl = w2l;
    } else return;
    ushort h = f2bf(v);
    th[i] = h;
    tl[i] = f2bf(v - bf2f(h));
}

// ---------------- bf16-MFMA GEMM (hi/lo), optional fused attn / BN-stats epilogue ----------
// A: Ah/Al [M][K] bf16; B: Bh/Bl [N][K] bf16 (pre-transposed). BK=32, BM=64.
// 4 waves 2x2; wave tile 32 x (BN/2); frags MR=2 x NR=BN/32. OBF16: C written as bf16.
template<int BN, bool ATTN, bool STATS, bool OBF16>
__global__ __launch_bounds__(256) void gemm_fused(
    const ushort* __restrict__ Ah, const ushort* __restrict__ Al,
    const ushort* __restrict__ Bh, const ushort* __restrict__ Bl,
    void* __restrict__ Cout, int M, int N, int K,
    const float* __restrict__ att_s, const float* __restrict__ att_d,
    float* __restrict__ a_src, float* __restrict__ a_dst,
    float* __restrict__ stats, int Cst)
{
    constexpr int BM = 64;
    constexpr int MR = 2, NR = BN / 32;
    __shared__ ushort sAh[BM][40], sAl[BM][40];   // 80B row stride
    __shared__ ushort sBh[BN][40], sBl[BN][40];
    int tid = threadIdx.x;
    int lane = tid & 63, wave = tid >> 6;
    int wr = wave >> 1, wc = wave & 1;
    int bm = blockIdx.y * BM, bn = blockIdx.x * BN;
    int mrow = lane & 15, kb = lane >> 4;

    int ar = tid >> 2, akc = tid & 3;
    int arow = bm + ar;
    bool aval = arow < M;
    size_t aoff = (size_t)(aval ? arow : 0) * K + akc * 8;
    int br, bkc;
    if constexpr (BN == 128) { br = tid >> 1; bkc = (tid & 1) * 2; }
    else { br = tid >> 2; bkc = tid & 3; }
    size_t boff = (size_t)(bn + br) * K + bkc * 8;

    f32x4 acc[MR][NR];
    #pragma unroll
    for (int i = 0; i < MR; ++i)
        #pragma unroll
        for (int j = 0; j < NR; ++j)
            acc[i][j] = (f32x4){0.f, 0.f, 0.f, 0.f};

    for (int k0 = 0; k0 < K; k0 += 32) {
        int4 vah = {0,0,0,0}, val4 = {0,0,0,0};
        if (aval) {
            vah  = *(const int4*)(Ah + aoff + k0);
            val4 = *(const int4*)(Al + aoff + k0);
        }
        int4 vbh0 = *(const int4*)(Bh + boff + k0);
        int4 vbl0 = *(const int4*)(Bl + boff + k0);
        int4 vbh1, vbl1;
        if constexpr (BN == 128) {
            vbh1 = *(const int4*)(Bh + boff + k0 + 8);
            vbl1 = *(const int4*)(Bl + boff + k0 + 8);
        }
        __syncthreads();
        *(int4*)&sAh[ar][akc * 8] = vah;
        *(int4*)&sAl[ar][akc * 8] = val4;
        *(int4*)&sBh[br][bkc * 8] = vbh0;
        *(int4*)&sBl[br][bkc * 8] = vbl0;
        if constexpr (BN == 128) {
            *(int4*)&sBh[br][(bkc + 1) * 8] = vbh1;
            *(int4*)&sBl[br][(bkc + 1) * 8] = vbl1;
        }
        __syncthreads();

        bf16x8 fah[MR], fal[MR], fbh[NR], fbl[NR];
        #pragma unroll
        for (int fi = 0; fi < MR; ++fi) {
            int r = wr * 32 + fi * 16 + mrow;
            fah[fi] = *(const bf16x8*)&sAh[r][kb * 8];
            fal[fi] = *(const bf16x8*)&sAl[r][kb * 8];
        }
        #pragma unroll
        for (int fj = 0; fj < NR; ++fj) {
            int c = wc * (BN / 2) + fj * 16 + mrow;
            fbh[fj] = *(const bf16x8*)&sBh[c][kb * 8];
            fbl[fj] = *(const bf16x8*)&sBl[c][kb * 8];
        }
        #pragma unroll
        for (int fi = 0; fi < MR; ++fi)
            #pragma unroll
            for (int fj = 0; fj < NR; ++fj) {
                acc[fi][fj] = __builtin_amdgcn_mfma_f32_16x16x32_bf16(fah[fi], fbh[fj], acc[fi][fj], 0, 0, 0);
                acc[fi][fj] = __builtin_amdgcn_mfma_f32_16x16x32_bf16(fah[fi], fbl[fj], acc[fi][fj], 0, 0, 0);
                acc[fi][fj] = __builtin_amdgcn_mfma_f32_16x16x32_bf16(fal[fi], fbh[fj], acc[fi][fj], 0, 0, 0);
            }
    }

    // C write: row = bm + wr*32 + fi*16 + (lane>>4)*4 + r ; col = bn + wc*(BN/2) + fj*16 + mrow
    #pragma unroll
    for (int fi = 0; fi < MR; ++fi) {
        int crow0 = bm + wr * 32 + fi * 16 + (lane >> 4) * 4;
        #pragma unroll
        for (int fj = 0; fj < NR; ++fj) {
            int ccol = bn + wc * (BN / 2) + fj * 16 + mrow;
            #pragma unroll
            for (int r = 0; r < 4; ++r) {
                int row = crow0 + r;
                if (row < M) {
                    if constexpr (OBF16)
                        ((ushort*)Cout)[(size_t)row * N + ccol] = f2bf(acc[fi][fj][r]);
                    else
                        ((float*)Cout)[(size_t)row * N + ccol] = acc[fi][fj][r];
                }
            }
        }
    }

    if constexpr (ATTN) {
        int hd = bn >> 8;
        float as_v[NR], ad_v[NR];
        #pragma unroll
        for (int fj = 0; fj < NR; ++fj) {
            int c = bn + wc * (BN / 2) + fj * 16 + mrow;
            as_v[fj] = att_s[c];
            ad_v[fj] = att_d[c];
        }
        #pragma unroll
        for (int fi = 0; fi < MR; ++fi)
            #pragma unroll
            for (int r = 0; r < 4; ++r) {
                float ss = 0.f, sd = 0.f;
                #pragma unroll
                for (int fj = 0; fj < NR; ++fj) {
                    float v = acc[fi][fj][r];
                    ss = fmaf(v, as_v[fj], ss);
                    sd = fmaf(v, ad_v[fj], sd);
                }
                #pragma unroll
                for (int off = 1; off < 16; off <<= 1) {
                    ss += __shfl_xor(ss, off);
                    sd += __shfl_xor(sd, off);
                }
                if (mrow == 0) {
                    int row = bm + wr * 32 + fi * 16 + (lane >> 4) * 4 + r;
                    if (row < M) {
                        atomicAdd(&a_src[2 * row + hd], ss);
                        atomicAdd(&a_dst[2 * row + hd], sd);
                    }
                }
            }
    }

    if constexpr (STATS) {
        #pragma unroll
        for (int fj = 0; fj < NR; ++fj) {
            float s = 0.f, s2 = 0.f;
            #pragma unroll
            for (int fi = 0; fi < MR; ++fi)
                #pragma unroll
                for (int r = 0; r < 4; ++r) {
                    float v = acc[fi][fj][r];
                    s += v;
                    s2 = fmaf(v, v, s2);
                }
            s  += __shfl_xor(s, 16);  s  += __shfl_xor(s, 32);
            s2 += __shfl_xor(s2, 16); s2 += __shfl_xor(s2, 32);
            if (lane < 16) {
                int c = bn + wc * (BN / 2) + fj * 16 + lane;
                atomicAdd(&stats[c], s);
                atomicAdd(&stats[Cst + c], s2);
            }
        }
    }
}

// ---------------- degree histogram over dst (incl. self-loops) ----------------
__global__ __launch_bounds__(256) void hist_kernel(const int* __restrict__ ei, int* __restrict__ deg)
{
    int e = blockIdx.x * 256 + threadIdx.x;
    if (e >= ETOT) return;
    int d = (e < NEDGES) ? ei[NEDGES + e] : (e - NEDGES);
    atomicAdd(&deg[d], 1);
}

// ---------------- single-block exclusive scan of deg -> row_start ----------------
__global__ __launch_bounds__(256) void scan_kernel(const int* __restrict__ deg, int* __restrict__ rowst)
{
    __shared__ int part[256];
    int t = threadIdx.x;
    const int chunk = (NNODES + 255) / 256;
    int base = t * chunk;
    int s = 0;
    for (int i = 0; i < chunk; ++i) {
        int n = base + i;
        if (n < NNODES) s += deg[n];
    }
    part[t] = s;
    __syncthreads();
    for (int off = 1; off < 256; off <<= 1) {
        int v = 0;
        if (t >= off) v = part[t - off];
        __syncthreads();
        if (t >= off) part[t] += v;
        __syncthreads();
    }
    int run = (t == 0) ? 0 : part[t - 1];
    for (int i = 0; i < chunk; ++i) {
        int n = base + i;
        if (n < NNODES) { rowst[n] = run; run += deg[n]; }
    }
}

// ---------------- scatter edges into CSR slots; precompute p = exp(lrelu(e)) ----------------
__global__ __launch_bounds__(256) void scatter_kernel(const int* __restrict__ ei,
    const float* __restrict__ a_src, const float* __restrict__ a_dst,
    const int* __restrict__ rowst, int* __restrict__ cnt,
    int* __restrict__ esrc, float* __restrict__ p0, float* __restrict__ p1)
{
    int e = blockIdx.x * 256 + threadIdx.x;
    if (e >= ETOT) return;
    int s, d;
    if (e < NEDGES) { s = ei[e]; d = ei[NEDGES + e]; } else { s = d = e - NEDGES; }
    int pos = rowst[d] + atomicAdd(&cnt[d], 1);
    esrc[pos] = s;
    float e0 = a_src[2 * s] + a_dst[2 * d];
    e0 = (e0 > 0.f) ? e0 : 0.2f * e0;
    float e1 = a_src[2 * s + 1] + a_dst[2 * d + 1];
    e1 = (e1 > 0.f) ? e1 : 0.2f * e1;
    p0[pos] = expf(e0);
    p1[pos] = expf(e1);
}

// ---------------- per-node aggregation (bf16 h) -> lrelu -> bf16 hi/lo split ----------------
// 128 threads: thread t owns features [4t,4t+4); t<64 = head0 (p0), t>=64 = head1 (p1).
__global__ __launch_bounds__(128) void aggregate_kernel(const ushort* __restrict__ h,
    const int* __restrict__ rowst, const int* __restrict__ deg, const int* __restrict__ esrc,
    const float* __restrict__ p0, const float* __restrict__ p1,
    const float* __restrict__ b_conv, ushort* __restrict__ yh, ushort* __restrict__ yl)
{
    int n = blockIdx.x, t = threadIdx.x;
    int s = rowst[n], len = deg[n];
    const float* pp = (t < 64) ? p0 : p1;
    float a0 = 0.f, a1 = 0.f, a2 = 0.f, a3 = 0.f;
    float den = 0.f;
    for (int k = 0; k < len; ++k) {
        int src = esrc[s + k];
        float q = pp[s + k];
        ushort4 hv = ((const ushort4*)(h + (size_t)src * HD))[t];
        a0 = fmaf(q, bf2f(hv.x), a0);
        a1 = fmaf(q, bf2f(hv.y), a1);
        a2 = fmaf(q, bf2f(hv.z), a2);
        a3 = fmaf(q, bf2f(hv.w), a3);
        den += q;
    }
    float4 bc = *(const float4*)(b_conv + t * 4);
    float inv = 1.f / den;
    float o[4] = { a0 * inv + bc.x, a1 * inv + bc.y, a2 * inv + bc.z, a3 * inv + bc.w };
    ushort4 hq, lq;
    float v;
    v = (o[0] > 0.f) ? o[0] : 0.01f * o[0]; hq.x = f2bf(v); lq.x = f2bf(v - bf2f(hq.x));
    v = (o[1] > 0.f) ? o[1] : 0.01f * o[1]; hq.y = f2bf(v); lq.y = f2bf(v - bf2f(hq.y));
    v = (o[2] > 0.f) ? o[2] : 0.01f * o[2]; hq.z = f2bf(v); lq.z = f2bf(v - bf2f(hq.z));
    v = (o[3] > 0.f) ? o[3] : 0.01f * o[3]; hq.w = f2bf(v); lq.w = f2bf(v - bf2f(hq.w));
    ((ushort4*)(yh + (size_t)n * HD))[t] = hq;
    ((ushort4*)(yl + (size_t)n * HD))[t] = lq;
}

// ---------------- BN + lrelu -> bf16 hi/lo split ----------------
__global__ __launch_bounds__(256) void bn_split(const float* __restrict__ z, const float* __restrict__ sums,
    const float* __restrict__ g, const float* __restrict__ beta,
    ushort* __restrict__ hi, ushort* __restrict__ lo, int C)
{
    int i = blockIdx.x * 256 + threadIdx.x;
    if (i >= NNODES * C / 4) return;
    int c0 = (i * 4) & (C - 1);
    float4 zv = ((const float4*)z)[i];
    float o[4] = {zv.x, zv.y, zv.z, zv.w};
    ushort4 hq, lq;
    ushort* hp = (ushort*)&hq;
    ushort* lp = (ushort*)&lq;
    #pragma unroll
    for (int j = 0; j < 4; ++j) {
        int c = c0 + j;
        float m = sums[c] * (1.f / NNODES);
        float vv = sums[C + c] * (1.f / NNODES) - m * m;
        float r = rsqrtf(vv + 1e-5f);
        float xv = g[c] * (o[j] - m) * r + beta[c];
        xv = (xv > 0.f) ? xv : 0.01f * xv;
        hp[j] = f2bf(xv);
        lp[j] = f2bf(xv - bf2f(hp[j]));
    }
    ((ushort4*)hi)[i] = hq;
    ((ushort4*)lo)[i] = lq;
}

// ---------------- BN(64) + lrelu + dense3 fused -> y3 ----------------
__global__ __launch_bounds__(256) void bn_dense3(const float* __restrict__ z2,
    const float* __restrict__ st, const float* __restrict__ g, const float* __restrict__ beta,
    const float* __restrict__ w3, const float* __restrict__ b3, float* __restrict__ y3)
{
    __shared__ float wsm[192], msm[64], rsm[64], gsm[64], bsm[64];
    int t = threadIdx.x;
    if (t < 192) wsm[t] = w3[t];
    if (t < 64) {
        float m = st[t] * (1.f / NNODES);
        float v = st[64 + t] * (1.f / NNODES) - m * m;
        msm[t] = m; rsm[t] = rsqrtf(v + 1e-5f);
        gsm[t] = g[t]; bsm[t] = beta[t];
    }
    __syncthreads();
    int n = blockIdx.x * 256 + t;
    if (n >= NNODES) return;
    const float* zr = z2 + (size_t)n * 64;
    float o0 = b3[0], o1 = b3[1], o2 = b3[2];
    #pragma unroll
    for (int c = 0; c < 64; ++c) {
        float xv = zr[c];
        xv = gsm[c] * (xv - msm[c]) * rsm[c] + bsm[c];
        xv = (xv > 0.f) ? xv : 0.01f * xv;
        o0 = fmaf(xv, wsm[3 * c],     o0);
        o1 = fmaf(xv, wsm[3 * c + 1], o1);
        o2 = fmaf(xv, wsm[3 * c + 2], o2);
    }
    y3[3 * n] = o0; y3[3 * n + 1] = o1; y3[3 * n + 2] = o2;
}

// ---------------- pairwise euclidean distances [N,N], 4 cols/thread, NT f32x4 stores ----
__global__ __launch_bounds__(256) void dist_kernel(const float* __restrict__ y3, float* __restrict__ out)
{
    int j0 = (blockIdx.x * 256 + threadIdx.x) * 4;
    int i0 = blockIdx.y * 64;
    if (j0 >= NNODES) return;
    const float4* yp = (const float4*)(y3 + 3 * j0);
    float4 q0 = yp[0], q1 = yp[1], q2 = yp[2];
    float xj[4] = {q0.x, q0.w, q1.z, q2.y};
    float yj[4] = {q0.y, q1.x, q1.w, q2.z};
    float zj[4] = {q0.z, q1.y, q2.x, q2.w};
    int iend = (i0 + 64 < NNODES) ? (i0 + 64) : NNODES;
    for (int i = i0; i < iend; ++i) {
        float xi = y3[3 * i], yi = y3[3 * i + 1], zi = y3[3 * i + 2];
        f32x4 dv;
        #pragma unroll
        for (int u = 0; u < 4; ++u) {
            float dx = xi - xj[u], dy = yi - yj[u], dz = zi - zj[u];
            float d2 = fmaf(dx, dx, fmaf(dy, dy, dz * dz));
            dv[u] = (d2 > 1e-12f) ? sqrtf(d2) : 0.f;
        }
        __builtin_nontemporal_store(dv, (f32x4*)(out + (size_t)i * NNODES + j0));
    }
}

extern "C" void kernel_launch(void* const* d_in, const int* in_sizes, int n_in,
                              void* d_out, int out_size, void* d_ws, size_t ws_size,
                              hipStream_t stream)
{
    (void)in_sizes; (void)n_in; (void)out_size; (void)ws_size;
    const float* x      = (const float*)d_in[0];
    const int*   ei     = (const int*)  d_in[1];
    const float* w_conv = (const float*)d_in[2];
    const float* att_s  = (const float*)d_in[3];
    const float* att_d  = (const float*)d_in[4];
    const float* b_conv = (const float*)d_in[5];
    const float* w_a  = (const float*)d_in[6];
    const float* g_a  = (const float*)d_in[8];
    const float* be_a = (const float*)d_in[9];
    const float* w_1  = (const float*)d_in[10];
    const float* g_1  = (const float*)d_in[12];
    const float* be_1 = (const float*)d_in[13];
    const float* w_2  = (const float*)d_in[14];
    const float* g_2  = (const float*)d_in[16];
    const float* be_2 = (const float*)d_in[17];
    const float* w_3  = (const float*)d_in[18];
    const float* b_3  = (const float*)d_in[19];

    char* ws = (char*)d_ws;
    size_t off = 0;
    auto take = [&](size_t bytes) {
        char* p = ws + off;
        off = (off + bytes + 255) & ~(size_t)255;
        return p;
    };
    ushort* h   = (ushort*)take((size_t)NNODES * HD * 2);      // bf16 h
    float* z_a  = (float*)take((size_t)NNODES * 256 * 4);
    float* z_1  = (float*)take((size_t)NNODES * 128 * 4);
    float* z_2  = (float*)take((size_t)NNODES * 64 * 4);
    float* y3   = (float*)take((size_t)NNODES * 3 * 4);
    ushort* xh  = (ushort*)take((size_t)NNODES * FINF * 2);
    ushort* xl  = (ushort*)take((size_t)NNODES * FINF * 2);
    ushort* yh  = (ushort*)take((size_t)NNODES * HD * 2);
    ushort* yl  = (ushort*)take((size_t)NNODES * HD * 2);
    ushort* zah = (ushort*)take((size_t)NNODES * 256 * 2);
    ushort* zal = (ushort*)take((size_t)NNODES * 256 * 2);
    ushort* z1h = (ushort*)take((size_t)NNODES * 128 * 2);
    ushort* z1l = (ushort*)take((size_t)NNODES * 128 * 2);
    ushort* wch = (ushort*)take((size_t)512 * 512 * 2);
    ushort* wcl = (ushort*)take((size_t)512 * 512 * 2);
    ushort* wah = (ushort*)take((size_t)256 * 512 * 2);
    ushort* wal = (ushort*)take((size_t)256 * 512 * 2);
    ushort* w1h = (ushort*)take((size_t)128 * 256 * 2);
    ushort* w1l = (ushort*)take((size_t)128 * 256 * 2);
    ushort* w2h = (ushort*)take((size_t)64 * 128 * 2);
    ushort* w2l = (ushort*)take((size_t)64 * 128 * 2);
    int*   rowst= (int*)  take((size_t)NNODES * 4);
    int*   esrc = (int*)  take((size_t)ETOT * 4);
    float* p0   = (float*)take((size_t)ETOT * 4);
    float* p1   = (float*)take((size_t)ETOT * 4);
    // zeroed block: deg, cnt, stats x3, a_src, a_dst
    const size_t ZB = 40000 + 40000 + 2048 + 1024 + 512 + 80000 + 80000;
    char*  zblk = take(ZB);
    int*   deg  = (int*)(zblk);
    int*   cnt  = (int*)(zblk + 40000);
    float* stA  = (float*)(zblk + 80000);
    float* st1  = (float*)(zblk + 82048);
    float* st2  = (float*)(zblk + 83072);
    float* a_src= (float*)(zblk + 83584);
    float* a_dst= (float*)(zblk + 163584);

    hipMemsetAsync(zblk, 0, ZB, stream);

    dim3 b256(256), b128(128);
    const int MT = (NNODES + 63) / 64;   // 157

    prep_kernel<<<dim3(PE4 / 256), b256, 0, stream>>>(x, xh, xl,
        w_conv, wch, wcl, w_a, wah, wal, w_1, w1h, w1l, w_2, w2h, w2l);

    // h = x @ w_conv (bf16 out), fused attn coefficients
    gemm_fused<128, true, false, true><<<dim3(HD / 128, MT), b256, 0, stream>>>(
        xh, xl, wch, wcl, h, NNODES, HD, FINF, att_s, att_d, a_src, a_dst, nullptr, 0);

    hist_kernel<<<dim3((ETOT + 255) / 256), b256, 0, stream>>>(ei, deg);
    scan_kernel<<<dim3(1), b256, 0, stream>>>(deg, rowst);
    scatter_kernel<<<dim3((ETOT + 255) / 256), b256, 0, stream>>>(ei, a_src, a_dst, rowst, cnt, esrc, p0, p1);
    aggregate_kernel<<<dim3(NNODES), b128, 0, stream>>>(h, rowst, deg, esrc, p0, p1, b_conv, yh, yl);

    // densea 512->256 (stats fused) + BN/lrelu/split
    gemm_fused<128, false, true, false><<<dim3(256 / 128, MT), b256, 0, stream>>>(
        yh, yl, wah, wal, z_a, NNODES, 256, 512, nullptr, nullptr, nullptr, nullptr, stA, 256);
    bn_split<<<dim3((NNODES * 256 / 4 + 255) / 256), b256, 0, stream>>>(z_a, stA, g_a, be_a, zah, zal, 256);

    // dense1 256->128 (stats fused) + BN/lrelu/split
    gemm_fused<64, false, true, false><<<dim3(128 / 64, MT), b256, 0, stream>>>(
        zah, zal, w1h, w1l, z_1, NNODES, 128, 256, nullptr, nullptr, nullptr, nullptr, st1, 128);
    bn_split<<<dim3((NNODES * 128 / 4 + 255) / 256), b256, 0, stream>>>(z_1, st1, g_1, be_1, z1h, z1l, 128);

    // dense2 128->64 (stats fused)
    gemm_fused<64, false, true, false><<<dim3(64 / 64, MT), b256, 0, stream>>>(
        z1h, z1l, w2h, w2l, z_2, NNODES, 64, 128, nullptr, nullptr, nullptr, nullptr, st2, 64);

    // BN + lrelu + dense3 fused
    bn_dense3<<<dim3((NNODES + 255) / 256), b256, 0, stream>>>(z_2, st2, g_2, be_2, w_3, b_3, y3);

    // pairwise distances
    dist_kernel<<<dim3((NNODES + 1023) / 1024, (NNODES + 63) / 64), b256, 0, stream>>>(y3, (float*)d_out);
}

// Round 7
// 297.568 us; speedup vs baseline: 1.8192x; 1.1004x over previous
//
#include <hip/hip_runtime.h>
#include <math.h>

#define NNODES 10000
#define NEDGES 320000
#define ETOT   (NEDGES + NNODES)
#define FINF   512
#define HD     512     // H*D
#define DHEAD  256

typedef __attribute__((ext_vector_type(8))) _Float16 f16x8;
typedef __attribute__((ext_vector_type(8))) ushort u16x8;
typedef __attribute__((ext_vector_type(4))) float f32x4;

__device__ __forceinline__ ushort f2h(float f) {
    return __builtin_bit_cast(ushort, (_Float16)f);
}
__device__ __forceinline__ float h2f(ushort u) {
    return (float)__builtin_bit_cast(_Float16, u);
}

// ---------------- fused prep: transpose 4 weights to fp16 [N][K] + edge histogram ----------
#define PW1 (512 * 512)                  // w_conv
#define PW2 (PW1 + 256 * 512)            // w_a
#define PW3 (PW2 + 128 * 256)            // w_1
#define PW4 (PW3 + 64 * 128)             // w_2
#define PWE (PW4 + ETOT)                 // histogram range
__global__ __launch_bounds__(256) void prep_kernel(
    const float* __restrict__ wc, ushort* __restrict__ wch,
    const float* __restrict__ wa, ushort* __restrict__ wah,
    const float* __restrict__ w1, ushort* __restrict__ w1h,
    const float* __restrict__ w2, ushort* __restrict__ w2h,
    const int* __restrict__ ei, int* __restrict__ deg)
{
    int idx = blockIdx.x * 256 + threadIdx.x;
    if (idx >= PWE) return;
    if (idx >= PW4) {                    // histogram over dst (incl. self-loops)
        int e = idx - PW4;
        int d = (e < NEDGES) ? ei[NEDGES + e] : (e - NEDGES);
        atomicAdd(&deg[d], 1);
        return;
    }
    float v; ushort* th; int i;
    if (idx < PW1) {            // w_conv [512][512] -> T
        i = idx; int n = i >> 9, k = i & 511;
        v = wc[(size_t)k * 512 + n]; th = wch;
    } else if (idx < PW2) {     // w_a [512][256] -> [256][512]
        i = idx - PW1; int n = i >> 9, k = i & 511;
        v = wa[(size_t)k * 256 + n]; th = wah;
    } else if (idx < PW3) {     // w_1 [256][128] -> [128][256]
        i = idx - PW2; int n = i >> 8, k = i & 255;
        v = w1[(size_t)k * 128 + n]; th = w1h;
    } else {                    // w_2 [128][64] -> [64][128]
        i = idx - PW3; int n = i >> 7, k = i & 127;
        v = w2[(size_t)k * 64 + n]; th = w2h;
    }
    th[i] = f2h(v);
}

// ---------------- fp16-MFMA GEMM with fused A-transform / attn / BN-stats epilogues -------
// AMODE 0: A fp16 [M][K]. AMODE 1: A f32, cvt in staging. AMODE 2: A f32 + BN + lrelu.
// B: fp16 [N][K] (pre-transposed). BK=32, BM=64. 4 waves 2x2; frags MR=2 x NR=BN/32.
// OF16: C written as fp16.
template<int BN, int AMODE, bool ATTN, bool STATS, bool OF16>
__global__ __launch_bounds__(256) void gemm_f16(
    const void* __restrict__ Ain, const ushort* __restrict__ Bh,
    void* __restrict__ Cout, int M, int N, int K,
    const float* __restrict__ att_s, const float* __restrict__ att_d,
    float* __restrict__ a_src, float* __restrict__ a_dst,
    float* __restrict__ stats,
    const float* __restrict__ bnst, const float* __restrict__ bng,
    const float* __restrict__ bnbe)
{
    constexpr int BM = 64;
    constexpr int MR = 2, NR = BN / 32;
    __shared__ ushort sA[BM][40], sB[BN][40];   // 80B row stride: 2-way bank (free)
    __shared__ float bsc[256], bsh[256];        // BN scale/shift (AMODE 2, K<=256)
    int tid = threadIdx.x;
    int lane = tid & 63, wave = tid >> 6;
    int wr = wave >> 1, wc = wave & 1;
    int bm = blockIdx.y * BM, bn = blockIdx.x * BN;
    int mrow = lane & 15, kb = lane >> 4;

    if constexpr (AMODE == 2) {
        for (int c = tid; c < K; c += 256) {
            float m = bnst[c] * (1.f / NNODES);
            float var = bnst[K + c] * (1.f / NNODES) - m * m;
            float sc = bng[c] * rsqrtf(var + 1e-5f);
            bsc[c] = sc;
            bsh[c] = bnbe[c] - m * sc;
        }
        __syncthreads();
    }

    int ar = tid >> 2, akc = tid & 3;
    int arow = bm + ar;
    bool aval = arow < M;
    size_t aoff = (size_t)(aval ? arow : 0) * K + akc * 8;
    int br, bkc;
    if constexpr (BN == 128) { br = tid >> 1; bkc = (tid & 1) * 2; }
    else { br = tid >> 2; bkc = tid & 3; }
    size_t boff = (size_t)(bn + br) * K + bkc * 8;

    f32x4 acc[MR][NR];
    #pragma unroll
    for (int i = 0; i < MR; ++i)
        #pragma unroll
        for (int j = 0; j < NR; ++j)
            acc[i][j] = (f32x4){0.f, 0.f, 0.f, 0.f};

    for (int k0 = 0; k0 < K; k0 += 32) {
        int4 va;
        if constexpr (AMODE == 0) {
            va = aval ? *(const int4*)((const ushort*)Ain + aoff + k0) : (int4){0, 0, 0, 0};
        } else {
            u16x8 us = (u16x8)0;
            if (aval) {
                const float* ap = (const float*)Ain + aoff + k0;
                float4 f0 = *(const float4*)ap;
                float4 f1 = *(const float4*)(ap + 4);
                float vv[8] = {f0.x, f0.y, f0.z, f0.w, f1.x, f1.y, f1.z, f1.w};
                #pragma unroll
                for (int j = 0; j < 8; ++j) {
                    float v = vv[j];
                    if constexpr (AMODE == 2) {
                        int c = k0 + akc * 8 + j;
                        v = fmaf(v, bsc[c], bsh[c]);
                        v = (v > 0.f) ? v : 0.01f * v;
                    }
                    us[j] = f2h(v);
                }
            }
            va = __builtin_bit_cast(int4, us);
        }
        int4 vb0 = *(const int4*)(Bh + boff + k0);
        int4 vb1;
        if constexpr (BN == 128) vb1 = *(const int4*)(Bh + boff + k0 + 8);
        __syncthreads();
        *(int4*)&sA[ar][akc * 8] = va;
        *(int4*)&sB[br][bkc * 8] = vb0;
        if constexpr (BN == 128) *(int4*)&sB[br][(bkc + 1) * 8] = vb1;
        __syncthreads();

        f16x8 fa[MR], fb[NR];
        #pragma unroll
        for (int fi = 0; fi < MR; ++fi)
            fa[fi] = *(const f16x8*)&sA[wr * 32 + fi * 16 + mrow][kb * 8];
        #pragma unroll
        for (int fj = 0; fj < NR; ++fj)
            fb[fj] = *(const f16x8*)&sB[wc * (BN / 2) + fj * 16 + mrow][kb * 8];
        #pragma unroll
        for (int fi = 0; fi < MR; ++fi)
            #pragma unroll
            for (int fj = 0; fj < NR; ++fj)
                acc[fi][fj] = __builtin_amdgcn_mfma_f32_16x16x32_f16(fa[fi], fb[fj], acc[fi][fj], 0, 0, 0);
    }

    // C write: row = bm + wr*32 + fi*16 + (lane>>4)*4 + r ; col = bn + wc*(BN/2) + fj*16 + mrow
    #pragma unroll
    for (int fi = 0; fi < MR; ++fi) {
        int crow0 = bm + wr * 32 + fi * 16 + (lane >> 4) * 4;
        #pragma unroll
        for (int fj = 0; fj < NR; ++fj) {
            int ccol = bn + wc * (BN / 2) + fj * 16 + mrow;
            #pragma unroll
            for (int r = 0; r < 4; ++r) {
                int row = crow0 + r;
                if (row < M) {
                    if constexpr (OF16)
                        ((ushort*)Cout)[(size_t)row * N + ccol] = f2h(acc[fi][fj][r]);
                    else
                        ((float*)Cout)[(size_t)row * N + ccol] = acc[fi][fj][r];
                }
            }
        }
    }

    if constexpr (ATTN) {
        int hd = bn >> 8;
        float as_v[NR], ad_v[NR];
        #pragma unroll
        for (int fj = 0; fj < NR; ++fj) {
            int c = bn + wc * (BN / 2) + fj * 16 + mrow;
            as_v[fj] = att_s[c];
            ad_v[fj] = att_d[c];
        }
        #pragma unroll
        for (int fi = 0; fi < MR; ++fi)
            #pragma unroll
            for (int r = 0; r < 4; ++r) {
                float ss = 0.f, sd = 0.f;
                #pragma unroll
                for (int fj = 0; fj < NR; ++fj) {
                    float v = acc[fi][fj][r];
                    ss = fmaf(v, as_v[fj], ss);
                    sd = fmaf(v, ad_v[fj], sd);
                }
                #pragma unroll
                for (int off = 1; off < 16; off <<= 1) {
                    ss += __shfl_xor(ss, off);
                    sd += __shfl_xor(sd, off);
                }
                if (mrow == 0) {
                    int row = bm + wr * 32 + fi * 16 + (lane >> 4) * 4 + r;
                    if (row < M) {
                        atomicAdd(&a_src[2 * row + hd], ss);
                        atomicAdd(&a_dst[2 * row + hd], sd);
                    }
                }
            }
    }

    if constexpr (STATS) {
        #pragma unroll
        for (int fj = 0; fj < NR; ++fj) {
            float s = 0.f, s2 = 0.f;
            #pragma unroll
            for (int fi = 0; fi < MR; ++fi)
                #pragma unroll
                for (int r = 0; r < 4; ++r) {
                    float v = acc[fi][fj][r];
                    s += v;
                    s2 = fmaf(v, v, s2);
                }
            s  += __shfl_xor(s, 16);  s  += __shfl_xor(s, 32);
            s2 += __shfl_xor(s2, 16); s2 += __shfl_xor(s2, 32);
            if (lane < 16) {
                int c = bn + wc * (BN / 2) + fj * 16 + lane;
                atomicAdd(&stats[c], s);
                atomicAdd(&stats[N + c], s2);
            }
        }
    }
}

// ---------------- single-block exclusive scan of deg -> row_start ----------------
__global__ __launch_bounds__(256) void scan_kernel(const int* __restrict__ deg, int* __restrict__ rowst)
{
    __shared__ int part[256];
    int t = threadIdx.x;
    const int chunk = (NNODES + 255) / 256;
    int base = t * chunk;
    int s = 0;
    for (int i = 0; i < chunk; ++i) {
        int n = base + i;
        if (n < NNODES) s += deg[n];
    }
    part[t] = s;
    __syncthreads();
    for (int off = 1; off < 256; off <<= 1) {
        int v = 0;
        if (t >= off) v = part[t - off];
        __syncthreads();
        if (t >= off) part[t] += v;
        __syncthreads();
    }
    int run = (t == 0) ? 0 : part[t - 1];
    for (int i = 0; i < chunk; ++i) {
        int n = base + i;
        if (n < NNODES) { rowst[n] = run; run += deg[n]; }
    }
}

// ---------------- scatter edges into CSR slots; precompute p = exp(lrelu(e)) ----------------
__global__ __launch_bounds__(256) void scatter_kernel(const int* __restrict__ ei,
    const float* __restrict__ a_src, const float* __restrict__ a_dst,
    const int* __restrict__ rowst, int* __restrict__ cnt,
    int* __restrict__ esrc, float* __restrict__ p0, float* __restrict__ p1)
{
    int e = blockIdx.x * 256 + threadIdx.x;
    if (e >= ETOT) return;
    int s, d;
    if (e < NEDGES) { s = ei[e]; d = ei[NEDGES + e]; } else { s = d = e - NEDGES; }
    int pos = rowst[d] + atomicAdd(&cnt[d], 1);
    esrc[pos] = s;
    float e0 = a_src[2 * s] + a_dst[2 * d];
    e0 = (e0 > 0.f) ? e0 : 0.2f * e0;
    float e1 = a_src[2 * s + 1] + a_dst[2 * d + 1];
    e1 = (e1 > 0.f) ? e1 : 0.2f * e1;
    p0[pos] = expf(e0);
    p1[pos] = expf(e1);
}

// ---------------- per-node aggregation (fp16 h) -> lrelu -> fp16 y ----------------
// 128 threads: thread t owns features [4t,4t+4); t<64 = head0 (p0), t>=64 = head1 (p1).
__global__ __launch_bounds__(128) void aggregate_kernel(const ushort* __restrict__ h,
    const int* __restrict__ rowst, const int* __restrict__ deg, const int* __restrict__ esrc,
    const float* __restrict__ p0, const float* __restrict__ p1,
    const float* __restrict__ b_conv, ushort* __restrict__ yh)
{
    int n = blockIdx.x, t = threadIdx.x;
    int s = rowst[n], len = deg[n];
    const float* pp = (t < 64) ? p0 : p1;
    float a0 = 0.f, a1 = 0.f, a2 = 0.f, a3 = 0.f;
    float den = 0.f;
    for (int k = 0; k < len; ++k) {
        int src = esrc[s + k];
        float q = pp[s + k];
        ushort4 hv = ((const ushort4*)(h + (size_t)src * HD))[t];
        a0 = fmaf(q, h2f(hv.x), a0);
        a1 = fmaf(q, h2f(hv.y), a1);
        a2 = fmaf(q, h2f(hv.z), a2);
        a3 = fmaf(q, h2f(hv.w), a3);
        den += q;
    }
    float4 bc = *(const float4*)(b_conv + t * 4);
    float inv = 1.f / den;
    float o[4] = { a0 * inv + bc.x, a1 * inv + bc.y, a2 * inv + bc.z, a3 * inv + bc.w };
    ushort4 hq;
    float v;
    v = (o[0] > 0.f) ? o[0] : 0.01f * o[0]; hq.x = f2h(v);
    v = (o[1] > 0.f) ? o[1] : 0.01f * o[1]; hq.y = f2h(v);
    v = (o[2] > 0.f) ? o[2] : 0.01f * o[2]; hq.z = f2h(v);
    v = (o[3] > 0.f) ? o[3] : 0.01f * o[3]; hq.w = f2h(v);
    ((ushort4*)(yh + (size_t)n * HD))[t] = hq;
}

// ---------------- BN(64) + lrelu + dense3 fused -> y3 ----------------
__global__ __launch_bounds__(256) void bn_dense3(const float* __restrict__ z2,
    const float* __restrict__ st, const float* __restrict__ g, const float* __restrict__ beta,
    const float* __restrict__ w3, const float* __restrict__ b3, float* __restrict__ y3)
{
    __shared__ float wsm[192], msm[64], rsm[64], gsm[64], bsm[64];
    int t = threadIdx.x;
    if (t < 192) wsm[t] = w3[t];
    if (t < 64) {
        float m = st[t] * (1.f / NNODES);
        float v = st[64 + t] * (1.f / NNODES) - m * m;
        msm[t] = m; rsm[t] = rsqrtf(v + 1e-5f);
        gsm[t] = g[t]; bsm[t] = beta[t];
    }
    __syncthreads();
    int n = blockIdx.x * 256 + t;
    if (n >= NNODES) return;
    const float* zr = z2 + (size_t)n * 64;
    float o0 = b3[0], o1 = b3[1], o2 = b3[2];
    #pragma unroll
    for (int c = 0; c < 64; ++c) {
        float xv = zr[c];
        xv = gsm[c] * (xv - msm[c]) * rsm[c] + bsm[c];
        xv = (xv > 0.f) ? xv : 0.01f * xv;
        o0 = fmaf(xv, wsm[3 * c],     o0);
        o1 = fmaf(xv, wsm[3 * c + 1], o1);
        o2 = fmaf(xv, wsm[3 * c + 2], o2);
    }
    y3[3 * n] = o0; y3[3 * n + 1] = o1; y3[3 * n + 2] = o2;
}

// ---------------- pairwise euclidean distances [N,N], 4 cols/thread, NT f32x4 stores ----
__global__ __launch_bounds__(256) void dist_kernel(const float* __restrict__ y3, float* __restrict__ out)
{
    int j0 = (blockIdx.x * 256 + threadIdx.x) * 4;
    int i0 = blockIdx.y * 64;
    if (j0 >= NNODES) return;
    const float4* yp = (const float4*)(y3 + 3 * j0);
    float4 q0 = yp[0], q1 = yp[1], q2 = yp[2];
    float xj[4] = {q0.x, q0.w, q1.z, q2.y};
    float yj[4] = {q0.y, q1.x, q1.w, q2.z};
    float zj[4] = {q0.z, q1.y, q2.x, q2.w};
    int iend = (i0 + 64 < NNODES) ? (i0 + 64) : NNODES;
    for (int i = i0; i < iend; ++i) {
        float xi = y3[3 * i], yi = y3[3 * i + 1], zi = y3[3 * i + 2];
        f32x4 dv;
        #pragma unroll
        for (int u = 0; u < 4; ++u) {
            float dx = xi - xj[u], dy = yi - yj[u], dz = zi - zj[u];
            float d2 = fmaf(dx, dx, fmaf(dy, dy, dz * dz));
            dv[u] = (d2 > 1e-12f) ? sqrtf(d2) : 0.f;
        }
        __builtin_nontemporal_store(dv, (f32x4*)(out + (size_t)i * NNODES + j0));
    }
}

extern "C" void kernel_launch(void* const* d_in, const int* in_sizes, int n_in,
                              void* d_out, int out_size, void* d_ws, size_t ws_size,
                              hipStream_t stream)
{
    (void)in_sizes; (void)n_in; (void)out_size; (void)ws_size;
    const float* x      = (const float*)d_in[0];
    const int*   ei     = (const int*)  d_in[1];
    const float* w_conv = (const float*)d_in[2];
    const float* att_s  = (const float*)d_in[3];
    const float* att_d  = (const float*)d_in[4];
    const float* b_conv = (const float*)d_in[5];
    const float* w_a  = (const float*)d_in[6];
    const float* g_a  = (const float*)d_in[8];
    const float* be_a = (const float*)d_in[9];
    const float* w_1  = (const float*)d_in[10];
    const float* g_1  = (const float*)d_in[12];
    const float* be_1 = (const float*)d_in[13];
    const float* w_2  = (const float*)d_in[14];
    const float* g_2  = (const float*)d_in[16];
    const float* be_2 = (const float*)d_in[17];
    const float* w_3  = (const float*)d_in[18];
    const float* b_3  = (const float*)d_in[19];

    char* ws = (char*)d_ws;
    size_t off = 0;
    auto take = [&](size_t bytes) {
        char* p = ws + off;
        off = (off + bytes + 255) & ~(size_t)255;
        return p;
    };
    ushort* h   = (ushort*)take((size_t)NNODES * HD * 2);      // fp16 h
    ushort* yh  = (ushort*)take((size_t)NNODES * HD * 2);      // fp16 y
    float* z_a  = (float*)take((size_t)NNODES * 256 * 4);
    float* z_1  = (float*)take((size_t)NNODES * 128 * 4);
    float* z_2  = (float*)take((size_t)NNODES * 64 * 4);
    float* y3   = (float*)take((size_t)NNODES * 3 * 4);
    ushort* wch = (ushort*)take((size_t)512 * 512 * 2);
    ushort* wah = (ushort*)take((size_t)256 * 512 * 2);
    ushort* w1h = (ushort*)take((size_t)128 * 256 * 2);
    ushort* w2h = (ushort*)take((size_t)64 * 128 * 2);
    int*   rowst= (int*)  take((size_t)NNODES * 4);
    int*   esrc = (int*)  take((size_t)ETOT * 4);
    float* p0   = (float*)take((size_t)ETOT * 4);
    float* p1   = (float*)take((size_t)ETOT * 4);
    // zeroed block: deg, cnt, stats x3, a_src, a_dst
    const size_t ZB = 40000 + 40000 + 2048 + 1024 + 512 + 80000 + 80000;
    char*  zblk = take(ZB);
    int*   deg  = (int*)(zblk);
    int*   cnt  = (int*)(zblk + 40000);
    float* stA  = (float*)(zblk + 80000);
    float* st1  = (float*)(zblk + 82048);
    float* st2  = (float*)(zblk + 83072);
    float* a_src= (float*)(zblk + 83584);
    float* a_dst= (float*)(zblk + 163584);

    hipMemsetAsync(zblk, 0, ZB, stream);

    dim3 b256(256), b128(128);
    const int MT = (NNODES + 63) / 64;   // 157

    // weights -> fp16 transposed, + degree histogram
    prep_kernel<<<dim3((PWE + 255) / 256), b256, 0, stream>>>(
        w_conv, wch, w_a, wah, w_1, w1h, w_2, w2h, ei, deg);

    // h = x @ w_conv (fp16 out, x converted in staging), fused attn coefficients
    gemm_f16<128, 1, true, false, true><<<dim3(HD / 128, MT), b256, 0, stream>>>(
        x, wch, h, NNODES, HD, FINF, att_s, att_d, a_src, a_dst, nullptr,
        nullptr, nullptr, nullptr);

    scan_kernel<<<dim3(1), b256, 0, stream>>>(deg, rowst);
    scatter_kernel<<<dim3((ETOT + 255) / 256), b256, 0, stream>>>(ei, a_src, a_dst, rowst, cnt, esrc, p0, p1);
    aggregate_kernel<<<dim3(NNODES), b128, 0, stream>>>(h, rowst, deg, esrc, p0, p1, b_conv, yh);

    // densea 512->256 (A = y fp16), stats fused
    gemm_f16<128, 0, false, true, false><<<dim3(256 / 128, MT), b256, 0, stream>>>(
        yh, wah, z_a, NNODES, 256, 512, nullptr, nullptr, nullptr, nullptr, stA,
        nullptr, nullptr, nullptr);

    // dense1 256->128 (A = BN(z_a)+lrelu in staging), stats fused
    gemm_f16<64, 2, false, true, false><<<dim3(128 / 64, MT), b256, 0, stream>>>(
        z_a, w1h, z_1, NNODES, 128, 256, nullptr, nullptr, nullptr, nullptr, st1,
        stA, g_a, be_a);

    // dense2 128->64 (A = BN(z_1)+lrelu in staging), stats fused
    gemm_f16<64, 2, false, true, false><<<dim3(64 / 64, MT), b256, 0, stream>>>(
        z_1, w2h, z_2, NNODES, 64, 128, nullptr, nullptr, nullptr, nullptr, st2,
        st1, g_1, be_1);

    // BN + lrelu + dense3 fused
    bn_dense3<<<dim3((NNODES + 255) / 256), b256, 0, stream>>>(z_2, st2, g_2, be_2, w_3, b_3, y3);

    // pairwise distances
    dist_kernel<<<dim3((NNODES + 1023) / 1024, (NNODES + 63) / 64), b256, 0, stream>>>(y3, (float*)d_out);
}